// Round 5
// baseline (1147.168 us; speedup 1.0000x reference)
//
#include <hip/hip_runtime.h>
#include <hip/hip_fp16.h>
#include <math.h>

#define NN 100000
#define NE 1200000
#define NES (NE + NN)   // edges incl. self-loops
#define FIN 256
#define HID 64
#define NC 32
#define NBLK 391        // (NN + 255) / 256

// ---------------- fused histogram + degree ------------------------------------
__global__ __launch_bounds__(256) void k_histdeg(const int* __restrict__ dst,
                                                 const float* __restrict__ ew,
                                                 int* __restrict__ cnt,
                                                 float* __restrict__ deg) {
    int e = blockIdx.x * 256 + threadIdx.x;
    if (e >= NES) return;
    int d; float w;
    if (e < NE) { d = dst[e]; w = ew[e]; } else { d = e - NE; w = 1.f; }
    atomicAdd(&cnt[d], 1);
    atomicAdd(&deg[d], w);
}
__global__ __launch_bounds__(256) void k_dinv(float* deg) {
    int i = blockIdx.x * 256 + threadIdx.x;
    if (i < NN) { float v = deg[i]; deg[i] = (v > 0.f) ? rsqrtf(v) : 0.f; }
}

// ---------------- CSR build: scan, fill ---------------------------------------
__global__ __launch_bounds__(256) void k_scanA(int* __restrict__ cnt,
                                               int* __restrict__ row_ptr,
                                               int* __restrict__ bsum) {
    __shared__ int tmp[256];
    int tid = threadIdx.x;
    int i = blockIdx.x * 256 + tid;
    int v = (i < NN) ? cnt[i] : 0;
    if (i < NN) cnt[i] = 0;          // re-zero: cnt becomes the fill cursor
    tmp[tid] = v;
    __syncthreads();
    for (int off = 1; off < 256; off <<= 1) {
        int t = (tid >= off) ? tmp[tid - off] : 0;
        __syncthreads();
        tmp[tid] += t;
        __syncthreads();
    }
    if (i < NN) row_ptr[i] = tmp[tid] - v;   // exclusive within block
    if (tid == 255) bsum[blockIdx.x] = tmp[255];
}

__global__ __launch_bounds__(512) void k_scanB(int* __restrict__ bsum) {
    __shared__ int tmp[512];
    int tid = threadIdx.x;
    int v = (tid < NBLK) ? bsum[tid] : 0;
    tmp[tid] = v;
    __syncthreads();
    for (int off = 1; off < 512; off <<= 1) {
        int t = (tid >= off) ? tmp[tid - off] : 0;
        __syncthreads();
        tmp[tid] += t;
        __syncthreads();
    }
    if (tid < NBLK) bsum[tid] = tmp[tid] - v;  // exclusive block offsets
}

__global__ __launch_bounds__(256) void k_scanC(int* __restrict__ row_ptr,
                                               const int* __restrict__ bsum) {
    int i = blockIdx.x * 256 + threadIdx.x;
    if (i < NN) row_ptr[i] += bsum[i >> 8];
    if (i == 0) row_ptr[NN] = NES;
}

__global__ __launch_bounds__(256) void k_fill(const int* __restrict__ src,
                                              const int* __restrict__ dst,
                                              const float* __restrict__ ew,
                                              const int* __restrict__ row_ptr,
                                              int* __restrict__ cur,
                                              int* __restrict__ src_sorted,
                                              float* __restrict__ w_sorted) {
    int e = blockIdx.x * 256 + threadIdx.x;
    if (e >= NES) return;
    int s, d; float w;
    if (e < NE) { s = src[e]; d = dst[e]; w = ew[e]; } else { s = d = e - NE; w = 1.f; }
    int pos = row_ptr[d] + atomicAdd(&cur[d], 1);
    src_sorted[pos] = s;
    w_sorted[pos] = w;
}

// ---------------- pipelined tiled GEMM core: C[M,N] = A[M,K] @ W[K,N] ---------
// 256 threads, per-thread 4x4 tile. Double-buffered LDS (one barrier/chunk:
// chunk i+1 writes the other buffer while laggards read chunk i; the barrier
// transitively protects buffer reuse two iterations later). Register prefetch
// of chunk k+1 overlaps global latency with the FMA block. float4 staging.
template<int N>
__device__ __forceinline__ void gemm_core(const float* __restrict__ A,
                                          const float* __restrict__ W,
                                          int K, int row0,
                                          float* __restrict__ As,   // [2][ROWS*36]
                                          float* __restrict__ Ws,   // [2][32*N]
                                          float acc[4][4]) {
    constexpr int TX = N / 4;
    constexpr int ROWS = 4 * (256 / TX);
    constexpr int ASZ = ROWS * 36, WSZ = 32 * N;
    constexpr int NA4 = ROWS * 8 / 256;   // float4 A loads per thread
    constexpr int NW4 = N / 32;           // float4 W loads per thread
    const int tid = threadIdx.x;
    const int tx = tid % TX, ty = tid / TX;
    float4 ra[NA4], rw[NW4];

    #pragma unroll
    for (int i = 0; i < 4; ++i)
        #pragma unroll
        for (int j = 0; j < 4; ++j) acc[i][j] = 0.f;

    // prefetch chunk 0
    #pragma unroll
    for (int u = 0; u < NA4; ++u) {
        int i = tid + u * 256, r = i >> 3, kq = (i & 7) * 4;
        int gr = row0 + r; if (gr > NN - 1) gr = NN - 1;
        ra[u] = *(const float4*)&A[(size_t)gr * K + kq];
    }
    #pragma unroll
    for (int u = 0; u < NW4; ++u)
        rw[u] = *(const float4*)&W[(size_t)(tid + u * 256) * 4];

    int buf = 0;
    for (int kc = 0; kc < K; kc += 32) {
        float* sA = As + buf * ASZ;
        float* sW = Ws + buf * WSZ;
        #pragma unroll
        for (int u = 0; u < NA4; ++u) {
            int i = tid + u * 256, r = i >> 3, kq = (i & 7) * 4;
            *(float4*)&sA[r * 36 + kq] = ra[u];
        }
        #pragma unroll
        for (int u = 0; u < NW4; ++u)
            *(float4*)&sW[(tid + u * 256) * 4] = rw[u];
        __syncthreads();
        if (kc + 32 < K) {            // prefetch next chunk (overlaps compute)
            int kn = kc + 32;
            #pragma unroll
            for (int u = 0; u < NA4; ++u) {
                int i = tid + u * 256, r = i >> 3, kq = (i & 7) * 4;
                int gr = row0 + r; if (gr > NN - 1) gr = NN - 1;
                ra[u] = *(const float4*)&A[(size_t)gr * K + kn + kq];
            }
            #pragma unroll
            for (int u = 0; u < NW4; ++u)
                rw[u] = *(const float4*)&W[(size_t)kn * N + (tid + u * 256) * 4];
        }
        #pragma unroll
        for (int kl = 0; kl < 32; kl += 4) {
            float4 a[4], w[4];
            #pragma unroll
            for (int i = 0; i < 4; ++i)
                a[i] = *(const float4*)&sA[(4 * ty + i) * 36 + kl];
            #pragma unroll
            for (int t = 0; t < 4; ++t)
                w[t] = *(const float4*)&sW[(kl + t) * N + 4 * tx];
            #pragma unroll
            for (int i = 0; i < 4; ++i) {
                const float* af = (const float*)&a[i];
                #pragma unroll
                for (int t = 0; t < 4; ++t) {
                    float s = af[t];
                    const float* wf = (const float*)&w[t];
                    acc[i][0] = fmaf(s, wf[0], acc[i][0]);
                    acc[i][1] = fmaf(s, wf[1], acc[i][1]);
                    acc[i][2] = fmaf(s, wf[2], acc[i][2]);
                    acc[i][3] = fmaf(s, wf[3], acc[i][3]);
                }
            }
        }
        buf ^= 1;
    }
}

// ---------------- pre-linear: xh = x @ W[K,64] + b; also fp16 copy ------------
__global__ __launch_bounds__(256) void k_pre(const float* __restrict__ A,
                                             const float* __restrict__ W,
                                             const float* __restrict__ b,
                                             float* __restrict__ out,
                                             __half2* __restrict__ out_h, int K) {
    __shared__ __align__(16) float As[2 * 64 * 36];
    __shared__ __align__(16) float Ws[2 * 32 * 64];
    float acc[4][4];
    int row0 = blockIdx.x * 64;
    gemm_core<64>(A, W, K, row0, As, Ws, acc);
    int tx = threadIdx.x % 16, ty = threadIdx.x / 16;
    float4 bb = *(const float4*)&b[tx * 4];
    #pragma unroll
    for (int i = 0; i < 4; ++i) {
        int row = row0 + 4 * ty + i;
        if (row < NN) {
            float4 o = { acc[i][0] + bb.x, acc[i][1] + bb.y,
                         acc[i][2] + bb.z, acc[i][3] + bb.w };
            *(float4*)&out[(size_t)row * 64 + tx * 4] = o;
            out_h[(size_t)row * 32 + 2 * tx]     = __floats2half2_rn(o.x, o.y);
            out_h[(size_t)row * 32 + 2 * tx + 1] = __floats2half2_rn(o.z, o.w);
        }
    }
}

// ---------------- GAT projection (fp16 xp) + attention scores -----------------
__global__ __launch_bounds__(256) void k_proj(const float* __restrict__ xh,
                                              const float* __restrict__ W,
                                              const float* __restrict__ att_s,
                                              const float* __restrict__ att_d,
                                              __half2* __restrict__ xp_h,
                                              float* __restrict__ a_src,
                                              float* __restrict__ a_dst) {
    __shared__ __align__(16) float As[2 * 32 * 36];
    __shared__ __align__(16) float Ws[2 * 32 * 128];
    float acc[4][4];
    int row0 = blockIdx.x * 32;
    gemm_core<128>(xh, W, 64, row0, As, Ws, acc);
    int tx = threadIdx.x % 32, ty = threadIdx.x / 32;
    int col = tx * 4, h = tx >> 4;
    float4 s4 = *(const float4*)&att_s[col];
    float4 d4 = *(const float4*)&att_d[col];
    float vs[4], vd[4];
    #pragma unroll
    for (int i = 0; i < 4; ++i) {
        int row = row0 + 4 * ty + i;
        if (row < NN) {
            xp_h[(size_t)row * 64 + 2 * tx]     = __floats2half2_rn(acc[i][0], acc[i][1]);
            xp_h[(size_t)row * 64 + 2 * tx + 1] = __floats2half2_rn(acc[i][2], acc[i][3]);
        }
        vs[i] = acc[i][0] * s4.x + acc[i][1] * s4.y + acc[i][2] * s4.z + acc[i][3] * s4.w;
        vd[i] = acc[i][0] * d4.x + acc[i][1] * d4.y + acc[i][2] * d4.z + acc[i][3] * d4.w;
    }
    #pragma unroll
    for (int off = 1; off < 16; off <<= 1) {
        #pragma unroll
        for (int i = 0; i < 4; ++i) {
            vs[i] += __shfl_xor(vs[i], off);
            vd[i] += __shfl_xor(vd[i], off);
        }
    }
    if ((tx & 15) == 0) {
        #pragma unroll
        for (int i = 0; i < 4; ++i) {
            int row = row0 + 4 * ty + i;
            if (row < NN) {
                a_src[row * 2 + h] = vs[i];
                a_dst[row * 2 + h] = vd[i];
            }
        }
    }
}

// ---------------- SG linear (64 rows/block) -----------------------------------
__global__ __launch_bounds__(256) void k_sgg(const float* __restrict__ sgh,
                                             const float* __restrict__ W,
                                             const float* __restrict__ b,
                                             float* __restrict__ xout) {
    __shared__ __align__(16) float As[2 * 64 * 36];
    __shared__ __align__(16) float Ws[2 * 32 * 64];
    float acc[4][4];
    int row0 = blockIdx.x * 64;
    gemm_core<64>(sgh, W, 64, row0, As, Ws, acc);
    int tx = threadIdx.x % 16, ty = threadIdx.x / 16;
    float4 bb = *(const float4*)&b[tx * 4];
    #pragma unroll
    for (int i = 0; i < 4; ++i) {
        int row = row0 + 4 * ty + i;
        if (row < NN) {
            float4 o;
            o.x = fmaxf(acc[i][0] + bb.x, 0.f);
            o.y = fmaxf(acc[i][1] + bb.y, 0.f);
            o.z = fmaxf(acc[i][2] + bb.z, 0.f);
            o.w = fmaxf(acc[i][3] + bb.w, 0.f);
            *(float4*)&xout[(size_t)row * 192 + 128 + tx * 4] = o;
        }
    }
}

// ---------------- classifier + log_softmax (128 rows/block) -------------------
__global__ __launch_bounds__(256) void k_cls(const float* __restrict__ x,
                                             const float* __restrict__ W,
                                             const float* __restrict__ b,
                                             float* __restrict__ out) {
    __shared__ __align__(16) float As[2 * 128 * 36];
    __shared__ __align__(16) float Ws[2 * 32 * 32];
    float acc[4][4];
    int row0 = blockIdx.x * 128;
    gemm_core<32>(x, W, 192, row0, As, Ws, acc);
    int tx = threadIdx.x % 8, ty = threadIdx.x / 8;
    float4 b4 = *(const float4*)&b[tx * 4];
    #pragma unroll
    for (int i = 0; i < 4; ++i) {
        int row = row0 + 4 * ty + i;
        float v0 = acc[i][0] + b4.x, v1 = acc[i][1] + b4.y;
        float v2 = acc[i][2] + b4.z, v3 = acc[i][3] + b4.w;
        float mx = fmaxf(fmaxf(v0, v1), fmaxf(v2, v3));
        #pragma unroll
        for (int off = 1; off < 8; off <<= 1) mx = fmaxf(mx, __shfl_xor(mx, off));
        float sm = __expf(v0 - mx) + __expf(v1 - mx) + __expf(v2 - mx) + __expf(v3 - mx);
        #pragma unroll
        for (int off = 1; off < 8; off <<= 1) sm += __shfl_xor(sm, off);
        float lg = mx + __logf(sm);
        if (row < NN) {
            float4 o = { v0 - lg, v1 - lg, v2 - lg, v3 - lg };
            *(float4*)&out[(size_t)row * 32 + tx * 4] = o;
        }
    }
}

// ---------------- fused GAT aggregation: one wave per dst node ----------------
__global__ __launch_bounds__(256) void k_gat_node(const int* __restrict__ row_ptr,
                                                  const int* __restrict__ src_sorted,
                                                  const float* __restrict__ a_src,
                                                  const float* __restrict__ a_dst,
                                                  const __half2* __restrict__ xp_h,
                                                  const float* __restrict__ gb,
                                                  float* __restrict__ xout) {
    int lane = threadIdx.x & 63;
    int d = blockIdx.x * 4 + (threadIdx.x >> 6);
    if (d >= NN) return;
    int p0 = row_ptr[d], p1 = row_ptr[d + 1];
    float ad0 = a_dst[2 * d], ad1 = a_dst[2 * d + 1];

    float m0 = -INFINITY, m1 = -INFINITY;
    for (int e = p0 + lane; e < p1; e += 64) {
        int s = src_sorted[e];
        float v0 = a_src[2 * s] + ad0;     v0 = (v0 > 0.f) ? v0 : 0.2f * v0;
        float v1 = a_src[2 * s + 1] + ad1; v1 = (v1 > 0.f) ? v1 : 0.2f * v1;
        m0 = fmaxf(m0, v0); m1 = fmaxf(m1, v1);
    }
    #pragma unroll
    for (int off = 32; off; off >>= 1) {
        m0 = fmaxf(m0, __shfl_xor(m0, off));
        m1 = fmaxf(m1, __shfl_xor(m1, off));
    }

    float s0 = 0.f, s1 = 0.f;
    for (int e = p0 + lane; e < p1; e += 64) {
        int s = src_sorted[e];
        float v0 = a_src[2 * s] + ad0;     v0 = (v0 > 0.f) ? v0 : 0.2f * v0;
        float v1 = a_src[2 * s + 1] + ad1; v1 = (v1 > 0.f) ? v1 : 0.2f * v1;
        s0 += __expf(v0 - m0); s1 += __expf(v1 - m1);
    }
    #pragma unroll
    for (int off = 32; off; off >>= 1) {
        s0 += __shfl_xor(s0, off);
        s1 += __shfl_xor(s1, off);
    }
    float inv0 = 1.f / (s0 + 1e-16f), inv1 = 1.f / (s1 + 1e-16f);

    float2 acc = { 0.f, 0.f };
    for (int base = p0; base < p1; base += 64) {
        int e = base + lane;
        float eal0 = 0.f, eal1 = 0.f; int es = 0;
        if (e < p1) {
            es = src_sorted[e];
            float v0 = a_src[2 * es] + ad0;     v0 = (v0 > 0.f) ? v0 : 0.2f * v0;
            float v1 = a_src[2 * es + 1] + ad1; v1 = (v1 > 0.f) ? v1 : 0.2f * v1;
            eal0 = __expf(v0 - m0) * inv0;
            eal1 = __expf(v1 - m1) * inv1;
        }
        int nn = min(64, p1 - base);
        for (int j = 0; j < nn; ++j) {
            float a0 = __shfl(eal0, j);
            float a1 = __shfl(eal1, j);
            int   s  = __shfl(es, j);
            float al = (lane < 32) ? a0 : a1;
            float2 f = __half22float2(xp_h[(size_t)s * 64 + lane]);
            acc.x = fmaf(al, f.x, acc.x);
            acc.y = fmaf(al, f.y, acc.y);
        }
    }
    float2 gb2 = ((const float2*)gb)[lane];
    float2 o = { fmaxf(acc.x + gb2.x, 0.f), fmaxf(acc.y + gb2.y, 0.f) };
    *(float2*)&xout[(size_t)d * 192 + 2 * lane] = o;
}

// ---------------- fused SG propagation: 2 edges/iter per wave -----------------
__global__ __launch_bounds__(256) void k_sg_node(const int* __restrict__ row_ptr,
                                                 const int* __restrict__ src_sorted,
                                                 const float* __restrict__ w_sorted,
                                                 const float* __restrict__ dinv,
                                                 const __half2* __restrict__ xh_h,
                                                 float* __restrict__ sgh) {
    int lane = threadIdx.x & 63;
    int d = blockIdx.x * 4 + (threadIdx.x >> 6);
    if (d >= NN) return;
    int p0 = row_ptr[d], p1 = row_ptr[d + 1];
    float did = dinv[d];
    int hf = lane >> 5, l32 = lane & 31;
    float2 acc = { 0.f, 0.f };
    for (int base = p0; base < p1; base += 2) {
        int e = base + hf;
        if (e < p1) {
            int s = src_sorted[e];
            float nrm = did * w_sorted[e] * dinv[s];
            float2 f = __half22float2(xh_h[(size_t)s * 32 + l32]);
            acc.x = fmaf(nrm, f.x, acc.x);
            acc.y = fmaf(nrm, f.y, acc.y);
        }
    }
    acc.x += __shfl_xor(acc.x, 32);
    acc.y += __shfl_xor(acc.y, 32);
    if (lane < 32)
        *(float2*)&sgh[(size_t)d * 64 + 2 * l32] = acc;
}

// ------------------------------------------------------------------------------
extern "C" void kernel_launch(void* const* d_in, const int* in_sizes, int n_in,
                              void* d_out, int out_size, void* d_ws, size_t ws_size,
                              hipStream_t stream) {
    const float* x   = (const float*)d_in[0];
    const int*   ei  = (const int*)d_in[1];
    const float* ew  = (const float*)d_in[2];
    const int* src = ei;
    const int* dst = ei + NE;

    const float* P[2][8];
    for (int l = 0; l < 2; ++l)
        for (int j = 0; j < 8; ++j)
            P[l][j] = (const float*)d_in[3 + l * 8 + j];
    const float* cls_W = (const float*)d_in[19];
    const float* cls_b = (const float*)d_in[20];

    float* ws = (float*)d_ws;
    const size_t n = NN;
    float* xh    = ws;                        // 64N  fp32
    float* u0    = ws + 64 * n;               // 64N  : xp_h (half) then sgh (fp32)
    __half2* xp_h = (__half2*)u0;
    float* sgh   = u0;
    __half2* xh_h = (__half2*)(ws + 128 * n); // 32N float-slots (64 halves/row)
    float* a_src = ws + 160 * n;              // 2N
    float* a_dst = ws + 162 * n;              // 2N
    float* dinv  = ws + 164 * n;              // N
    float* xA    = ws + 165 * n;              // 192N
    float* xB    = ws + 357 * n;              // 192N
    int*   row_ptr    = (int*)(ws + 549 * n);        // NN+1
    int*   cnt        = row_ptr + (NN + 1);          // NN (histogram, then cursor)
    int*   bsum       = cnt + NN;                    // 512
    int*   src_sorted = bsum + 512;                  // NES
    float* w_sorted   = (float*)(src_sorted + NES);  // NES

    const int TB = 256;
    int gb_edge = (NES + TB - 1) / TB;
    int gb_node = (NN + TB - 1) / TB;
    int gb_wave4 = (NN + 3) / 4;

    // ---- CSR build + degrees ----
    hipMemsetAsync(cnt, 0, NN * sizeof(int), stream);
    hipMemsetAsync(dinv, 0, n * sizeof(float), stream);
    k_histdeg<<<gb_edge, TB, 0, stream>>>(dst, ew, cnt, dinv);
    k_scanA<<<NBLK, TB, 0, stream>>>(cnt, row_ptr, bsum);
    k_scanB<<<1, 512, 0, stream>>>(bsum);
    k_scanC<<<gb_node, TB, 0, stream>>>(row_ptr, bsum);
    k_fill <<<gb_edge, TB, 0, stream>>>(src, dst, ew, row_ptr, cnt, src_sorted, w_sorted);
    k_dinv <<<gb_node, TB, 0, stream>>>(dinv);

    const float* xin = x;
    int K = FIN;
    for (int l = 0; l < 2; ++l) {
        const float* pre_W = P[l][0]; const float* pre_b = P[l][1];
        const float* gat_W = P[l][2]; const float* att_s = P[l][3];
        const float* att_d = P[l][4]; const float* gat_b = P[l][5];
        const float* sg_W  = P[l][6]; const float* sg_b  = P[l][7];
        float* xout = (l == 0) ? xA : xB;

        k_pre <<<(NN + 63) / 64, TB, 0, stream>>>(xin, pre_W, pre_b, xh, xh_h, K);
        k_proj<<<(NN + 31) / 32, TB, 0, stream>>>(xh, gat_W, att_s, att_d,
                                                  xp_h, a_src, a_dst);
        k_gat_node<<<gb_wave4, TB, 0, stream>>>(row_ptr, src_sorted, a_src, a_dst,
                                                xp_h, gat_b, xout);
        k_sg_node <<<gb_wave4, TB, 0, stream>>>(row_ptr, src_sorted, w_sorted, dinv,
                                                xh_h, sgh);
        k_sgg <<<(NN + 63) / 64, TB, 0, stream>>>(sgh, sg_W, sg_b, xout);

        xin = xout;
        K = 192;
    }

    k_cls<<<(NN + 127) / 128, TB, 0, stream>>>(xB, cls_W, cls_b, (float*)d_out);
}

// Round 6
// 917.096 us; speedup vs baseline: 1.2509x; 1.2509x over previous
//
#include <hip/hip_runtime.h>
#include <hip/hip_fp16.h>
#include <math.h>

#define NN 100000
#define NE 1200000
#define NES (NE + NN)   // edges incl. self-loops
#define FIN 256
#define HID 64
#define NC 32
#define NBLK 391        // (NN + 255) / 256

// ---------------- fused histogram + degree ------------------------------------
__global__ __launch_bounds__(256) void k_histdeg(const int* __restrict__ dst,
                                                 const float* __restrict__ ew,
                                                 int* __restrict__ cnt,
                                                 float* __restrict__ deg) {
    int e = blockIdx.x * 256 + threadIdx.x;
    if (e >= NES) return;
    int d; float w;
    if (e < NE) { d = dst[e]; w = ew[e]; } else { d = e - NE; w = 1.f; }
    atomicAdd(&cnt[d], 1);
    atomicAdd(&deg[d], w);
}
__global__ __launch_bounds__(256) void k_dinv(float* deg) {
    int i = blockIdx.x * 256 + threadIdx.x;
    if (i < NN) { float v = deg[i]; deg[i] = (v > 0.f) ? rsqrtf(v) : 0.f; }
}

// ---------------- CSR build: scan, fill ---------------------------------------
__global__ __launch_bounds__(256) void k_scanA(int* __restrict__ cnt,
                                               int* __restrict__ row_ptr,
                                               int* __restrict__ bsum) {
    __shared__ int tmp[256];
    int tid = threadIdx.x;
    int i = blockIdx.x * 256 + tid;
    int v = (i < NN) ? cnt[i] : 0;
    if (i < NN) cnt[i] = 0;          // re-zero: cnt becomes the fill cursor
    tmp[tid] = v;
    __syncthreads();
    for (int off = 1; off < 256; off <<= 1) {
        int t = (tid >= off) ? tmp[tid - off] : 0;
        __syncthreads();
        tmp[tid] += t;
        __syncthreads();
    }
    if (i < NN) row_ptr[i] = tmp[tid] - v;   // exclusive within block
    if (tid == 255) bsum[blockIdx.x] = tmp[255];
}

__global__ __launch_bounds__(512) void k_scanB(int* __restrict__ bsum) {
    __shared__ int tmp[512];
    int tid = threadIdx.x;
    int v = (tid < NBLK) ? bsum[tid] : 0;
    tmp[tid] = v;
    __syncthreads();
    for (int off = 1; off < 512; off <<= 1) {
        int t = (tid >= off) ? tmp[tid - off] : 0;
        __syncthreads();
        tmp[tid] += t;
        __syncthreads();
    }
    if (tid < NBLK) bsum[tid] = tmp[tid] - v;  // exclusive block offsets
}

__global__ __launch_bounds__(256) void k_scanC(int* __restrict__ row_ptr,
                                               const int* __restrict__ bsum) {
    int i = blockIdx.x * 256 + threadIdx.x;
    if (i < NN) row_ptr[i] += bsum[i >> 8];
    if (i == 0) row_ptr[NN] = NES;
}

// w_sorted stores w * dinv[src] (SG norm partially folded; GAT ignores w)
__global__ __launch_bounds__(256) void k_fill(const int* __restrict__ src,
                                              const int* __restrict__ dst,
                                              const float* __restrict__ ew,
                                              const int* __restrict__ row_ptr,
                                              int* __restrict__ cur,
                                              const float* __restrict__ dinv,
                                              int* __restrict__ src_sorted,
                                              float* __restrict__ w_sorted) {
    int e = blockIdx.x * 256 + threadIdx.x;
    if (e >= NES) return;
    int s, d; float w;
    if (e < NE) { s = src[e]; d = dst[e]; w = ew[e]; } else { s = d = e - NE; w = 1.f; }
    int pos = row_ptr[d] + atomicAdd(&cur[d], 1);
    src_sorted[pos] = s;
    w_sorted[pos] = w * dinv[s];
}

// ---------------- simple tiled GEMM core (short-K kernels) --------------------
template<int N>
__device__ __forceinline__ void gemm_core_s(const float* __restrict__ A,
                                            const float* __restrict__ W,
                                            int K, int row0,
                                            float* __restrict__ As,
                                            float* __restrict__ Ws,
                                            float acc[4][4]) {
    constexpr int TX = N / 4;
    constexpr int ROWS = 4 * (256 / TX);
    const int tid = threadIdx.x;
    const int tx = tid % TX, ty = tid / TX;
    #pragma unroll
    for (int i = 0; i < 4; ++i)
        #pragma unroll
        for (int j = 0; j < 4; ++j) acc[i][j] = 0.f;
    for (int kc = 0; kc < K; kc += 32) {
        __syncthreads();
        for (int i = tid; i < ROWS * 32; i += 256) {
            int r = i >> 5, kl = i & 31;
            int gr = row0 + r; if (gr > NN - 1) gr = NN - 1;
            As[r * 36 + kl] = A[(size_t)gr * K + kc + kl];
        }
        for (int i = tid; i < 32 * N; i += 256)
            Ws[i] = W[(size_t)kc * N + i];
        __syncthreads();
        #pragma unroll
        for (int kl = 0; kl < 32; kl += 4) {
            float4 a[4], w[4];
            #pragma unroll
            for (int i = 0; i < 4; ++i)
                a[i] = *(const float4*)&As[(4 * ty + i) * 36 + kl];
            #pragma unroll
            for (int t = 0; t < 4; ++t)
                w[t] = *(const float4*)&Ws[(kl + t) * N + 4 * tx];
            #pragma unroll
            for (int i = 0; i < 4; ++i) {
                const float* af = (const float*)&a[i];
                #pragma unroll
                for (int t = 0; t < 4; ++t) {
                    float s = af[t];
                    const float* wf = (const float*)&w[t];
                    acc[i][0] = fmaf(s, wf[0], acc[i][0]);
                    acc[i][1] = fmaf(s, wf[1], acc[i][1]);
                    acc[i][2] = fmaf(s, wf[2], acc[i][2]);
                    acc[i][3] = fmaf(s, wf[3], acc[i][3]);
                }
            }
        }
    }
}

// ---------------- pipelined GEMM core (long-K: k_pre only) --------------------
template<int N>
__device__ __forceinline__ void gemm_core_p(const float* __restrict__ A,
                                            const float* __restrict__ W,
                                            int K, int row0,
                                            float* __restrict__ As,   // [2][ROWS*36]
                                            float* __restrict__ Ws,   // [2][32*N]
                                            float acc[4][4]) {
    constexpr int TX = N / 4;
    constexpr int ROWS = 4 * (256 / TX);
    constexpr int ASZ = ROWS * 36, WSZ = 32 * N;
    constexpr int NA4 = ROWS * 8 / 256;
    constexpr int NW4 = N / 32;
    const int tid = threadIdx.x;
    const int tx = tid % TX, ty = tid / TX;
    float4 ra[NA4], rw[NW4];

    #pragma unroll
    for (int i = 0; i < 4; ++i)
        #pragma unroll
        for (int j = 0; j < 4; ++j) acc[i][j] = 0.f;

    #pragma unroll
    for (int u = 0; u < NA4; ++u) {
        int i = tid + u * 256, r = i >> 3, kq = (i & 7) * 4;
        int gr = row0 + r; if (gr > NN - 1) gr = NN - 1;
        ra[u] = *(const float4*)&A[(size_t)gr * K + kq];
    }
    #pragma unroll
    for (int u = 0; u < NW4; ++u)
        rw[u] = *(const float4*)&W[(size_t)(tid + u * 256) * 4];

    int buf = 0;
    for (int kc = 0; kc < K; kc += 32) {
        float* sA = As + buf * ASZ;
        float* sW = Ws + buf * WSZ;
        #pragma unroll
        for (int u = 0; u < NA4; ++u) {
            int i = tid + u * 256, r = i >> 3, kq = (i & 7) * 4;
            *(float4*)&sA[r * 36 + kq] = ra[u];
        }
        #pragma unroll
        for (int u = 0; u < NW4; ++u)
            *(float4*)&sW[(tid + u * 256) * 4] = rw[u];
        __syncthreads();
        if (kc + 32 < K) {
            int kn = kc + 32;
            #pragma unroll
            for (int u = 0; u < NA4; ++u) {
                int i = tid + u * 256, r = i >> 3, kq = (i & 7) * 4;
                int gr = row0 + r; if (gr > NN - 1) gr = NN - 1;
                ra[u] = *(const float4*)&A[(size_t)gr * K + kn + kq];
            }
            #pragma unroll
            for (int u = 0; u < NW4; ++u)
                rw[u] = *(const float4*)&W[(size_t)kn * N + (tid + u * 256) * 4];
        }
        #pragma unroll
        for (int kl = 0; kl < 32; kl += 4) {
            float4 a[4], w[4];
            #pragma unroll
            for (int i = 0; i < 4; ++i)
                a[i] = *(const float4*)&sA[(4 * ty + i) * 36 + kl];
            #pragma unroll
            for (int t = 0; t < 4; ++t)
                w[t] = *(const float4*)&sW[(kl + t) * N + 4 * tx];
            #pragma unroll
            for (int i = 0; i < 4; ++i) {
                const float* af = (const float*)&a[i];
                #pragma unroll
                for (int t = 0; t < 4; ++t) {
                    float s = af[t];
                    const float* wf = (const float*)&w[t];
                    acc[i][0] = fmaf(s, wf[0], acc[i][0]);
                    acc[i][1] = fmaf(s, wf[1], acc[i][1]);
                    acc[i][2] = fmaf(s, wf[2], acc[i][2]);
                    acc[i][3] = fmaf(s, wf[3], acc[i][3]);
                }
            }
        }
        buf ^= 1;
    }
}

// ---------------- pre-linear: xh = x @ W[K,64] + b ----------------------------
__global__ __launch_bounds__(256) void k_pre(const float* __restrict__ A,
                                             const float* __restrict__ W,
                                             const float* __restrict__ b,
                                             float* __restrict__ out, int K) {
    __shared__ __align__(16) float As[2 * 64 * 36];
    __shared__ __align__(16) float Ws[2 * 32 * 64];
    float acc[4][4];
    int row0 = blockIdx.x * 64;
    gemm_core_p<64>(A, W, K, row0, As, Ws, acc);
    int tx = threadIdx.x % 16, ty = threadIdx.x / 16;
    float4 bb = *(const float4*)&b[tx * 4];
    #pragma unroll
    for (int i = 0; i < 4; ++i) {
        int row = row0 + 4 * ty + i;
        if (row < NN) {
            float4 o = { acc[i][0] + bb.x, acc[i][1] + bb.y,
                         acc[i][2] + bb.z, acc[i][3] + bb.w };
            *(float4*)&out[(size_t)row * 64 + tx * 4] = o;
        }
    }
}

// ---------------- GAT projection (fp16 xp) + attention scores -----------------
__global__ __launch_bounds__(256) void k_proj(const float* __restrict__ xh,
                                              const float* __restrict__ W,
                                              const float* __restrict__ att_s,
                                              const float* __restrict__ att_d,
                                              __half2* __restrict__ xp_h,
                                              float* __restrict__ a_src,
                                              float* __restrict__ a_dst) {
    __shared__ __align__(16) float As[32 * 36];
    __shared__ __align__(16) float Ws[32 * 128];
    float acc[4][4];
    int row0 = blockIdx.x * 32;
    gemm_core_s<128>(xh, W, 64, row0, As, Ws, acc);
    int tx = threadIdx.x % 32, ty = threadIdx.x / 32;
    int col = tx * 4, h = tx >> 4;
    float4 s4 = *(const float4*)&att_s[col];
    float4 d4 = *(const float4*)&att_d[col];
    float vs[4], vd[4];
    #pragma unroll
    for (int i = 0; i < 4; ++i) {
        int row = row0 + 4 * ty + i;
        if (row < NN) {
            xp_h[(size_t)row * 64 + 2 * tx]     = __floats2half2_rn(acc[i][0], acc[i][1]);
            xp_h[(size_t)row * 64 + 2 * tx + 1] = __floats2half2_rn(acc[i][2], acc[i][3]);
        }
        vs[i] = acc[i][0] * s4.x + acc[i][1] * s4.y + acc[i][2] * s4.z + acc[i][3] * s4.w;
        vd[i] = acc[i][0] * d4.x + acc[i][1] * d4.y + acc[i][2] * d4.z + acc[i][3] * d4.w;
    }
    #pragma unroll
    for (int off = 1; off < 16; off <<= 1) {
        #pragma unroll
        for (int i = 0; i < 4; ++i) {
            vs[i] += __shfl_xor(vs[i], off);
            vd[i] += __shfl_xor(vd[i], off);
        }
    }
    if ((tx & 15) == 0) {
        #pragma unroll
        for (int i = 0; i < 4; ++i) {
            int row = row0 + 4 * ty + i;
            if (row < NN) {
                a_src[row * 2 + h] = vs[i];
                a_dst[row * 2 + h] = vd[i];
            }
        }
    }
}

// ---------------- SG pre-projection: xq = xh @ sg_W (fp16 out, no bias) -------
__global__ __launch_bounds__(256) void k_sgq(const float* __restrict__ xh,
                                             const float* __restrict__ W,
                                             __half2* __restrict__ xq_h) {
    __shared__ __align__(16) float As[64 * 36];
    __shared__ __align__(16) float Ws[32 * 64];
    float acc[4][4];
    int row0 = blockIdx.x * 64;
    gemm_core_s<64>(xh, W, 64, row0, As, Ws, acc);
    int tx = threadIdx.x % 16, ty = threadIdx.x / 16;
    #pragma unroll
    for (int i = 0; i < 4; ++i) {
        int row = row0 + 4 * ty + i;
        if (row < NN) {
            xq_h[(size_t)row * 32 + 2 * tx]     = __floats2half2_rn(acc[i][0], acc[i][1]);
            xq_h[(size_t)row * 32 + 2 * tx + 1] = __floats2half2_rn(acc[i][2], acc[i][3]);
        }
    }
}

// ---------------- classifier + log_softmax (128 rows/block) -------------------
__global__ __launch_bounds__(256) void k_cls(const float* __restrict__ x,
                                             const float* __restrict__ W,
                                             const float* __restrict__ b,
                                             float* __restrict__ out) {
    __shared__ __align__(16) float As[128 * 36];
    __shared__ __align__(16) float Ws[32 * 32];
    float acc[4][4];
    int row0 = blockIdx.x * 128;
    gemm_core_s<32>(x, W, 192, row0, As, Ws, acc);
    int tx = threadIdx.x % 8, ty = threadIdx.x / 8;
    float4 b4 = *(const float4*)&b[tx * 4];
    #pragma unroll
    for (int i = 0; i < 4; ++i) {
        int row = row0 + 4 * ty + i;
        float v0 = acc[i][0] + b4.x, v1 = acc[i][1] + b4.y;
        float v2 = acc[i][2] + b4.z, v3 = acc[i][3] + b4.w;
        float mx = fmaxf(fmaxf(v0, v1), fmaxf(v2, v3));
        #pragma unroll
        for (int off = 1; off < 8; off <<= 1) mx = fmaxf(mx, __shfl_xor(mx, off));
        float sm = __expf(v0 - mx) + __expf(v1 - mx) + __expf(v2 - mx) + __expf(v3 - mx);
        #pragma unroll
        for (int off = 1; off < 8; off <<= 1) sm += __shfl_xor(sm, off);
        float lg = mx + __logf(sm);
        if (row < NN) {
            float4 o = { v0 - lg, v1 - lg, v2 - lg, v3 - lg };
            *(float4*)&out[(size_t)row * 32 + tx * 4] = o;
        }
    }
}

// ---------------- fused GAT + SG aggregation: one wave per dst node -----------
// GAT: softmax(alpha)-weighted gather of xp rows -> xout[:,0:128]
// SG : (w*dinv_s)-weighted gather of xq rows, *dinv_d -> xout[:,128:192]
__global__ __launch_bounds__(256) void k_agg(const int* __restrict__ row_ptr,
                                             const int* __restrict__ src_sorted,
                                             const float* __restrict__ w_sorted,
                                             const float* __restrict__ dinv,
                                             const float* __restrict__ a_src,
                                             const float* __restrict__ a_dst,
                                             const __half2* __restrict__ xp_h,
                                             const __half*  __restrict__ xq_h,
                                             const float* __restrict__ gat_b,
                                             const float* __restrict__ sg_b,
                                             float* __restrict__ xout) {
    int lane = threadIdx.x & 63;
    int d = blockIdx.x * 4 + (threadIdx.x >> 6);
    if (d >= NN) return;
    int p0 = row_ptr[d], p1 = row_ptr[d + 1];
    int nn = p1 - p0;
    float2 ad2 = ((const float2*)a_dst)[d];

    float2 gacc = { 0.f, 0.f };
    float  sacc = 0.f;

    if (nn <= 64) {
        // ---- fast path (avg degree ~13): edge data lives in registers ----
        float v0 = -INFINITY, v1 = -INFINITY, ewq = 0.f; int es = 0;
        if (lane < nn) {
            es = src_sorted[p0 + lane];
            ewq = w_sorted[p0 + lane];
            float2 a2 = ((const float2*)a_src)[es];
            v0 = a2.x + ad2.x; v0 = (v0 > 0.f) ? v0 : 0.2f * v0;
            v1 = a2.y + ad2.y; v1 = (v1 > 0.f) ? v1 : 0.2f * v1;
        }
        float m0 = v0, m1 = v1;
        #pragma unroll
        for (int off = 32; off; off >>= 1) {
            m0 = fmaxf(m0, __shfl_xor(m0, off));
            m1 = fmaxf(m1, __shfl_xor(m1, off));
        }
        float e0 = (lane < nn) ? __expf(v0 - m0) : 0.f;
        float e1 = (lane < nn) ? __expf(v1 - m1) : 0.f;
        float s0 = e0, s1 = e1;
        #pragma unroll
        for (int off = 32; off; off >>= 1) {
            s0 += __shfl_xor(s0, off);
            s1 += __shfl_xor(s1, off);
        }
        float eal0 = e0 / (s0 + 1e-16f);
        float eal1 = e1 / (s1 + 1e-16f);
        for (int j = 0; j < nn; ++j) {
            float a0 = __shfl(eal0, j);
            float a1 = __shfl(eal1, j);
            float wq = __shfl(ewq, j);
            int   s  = __shfl(es, j);
            float al = (lane < 32) ? a0 : a1;
            float2 f = __half22float2(xp_h[(size_t)s * 64 + lane]);
            float xq = __half2float(xq_h[(size_t)s * 64 + lane]);
            gacc.x = fmaf(al, f.x, gacc.x);
            gacc.y = fmaf(al, f.y, gacc.y);
            sacc   = fmaf(wq, xq, sacc);
        }
    } else {
        // ---- generic 3-pass path (rare: degree > 64) ----
        float m0 = -INFINITY, m1 = -INFINITY;
        for (int e = p0 + lane; e < p1; e += 64) {
            int s = src_sorted[e];
            float2 a2 = ((const float2*)a_src)[s];
            float v0 = a2.x + ad2.x; v0 = (v0 > 0.f) ? v0 : 0.2f * v0;
            float v1 = a2.y + ad2.y; v1 = (v1 > 0.f) ? v1 : 0.2f * v1;
            m0 = fmaxf(m0, v0); m1 = fmaxf(m1, v1);
        }
        #pragma unroll
        for (int off = 32; off; off >>= 1) {
            m0 = fmaxf(m0, __shfl_xor(m0, off));
            m1 = fmaxf(m1, __shfl_xor(m1, off));
        }
        float s0 = 0.f, s1 = 0.f;
        for (int e = p0 + lane; e < p1; e += 64) {
            int s = src_sorted[e];
            float2 a2 = ((const float2*)a_src)[s];
            float v0 = a2.x + ad2.x; v0 = (v0 > 0.f) ? v0 : 0.2f * v0;
            float v1 = a2.y + ad2.y; v1 = (v1 > 0.f) ? v1 : 0.2f * v1;
            s0 += __expf(v0 - m0); s1 += __expf(v1 - m1);
        }
        #pragma unroll
        for (int off = 32; off; off >>= 1) {
            s0 += __shfl_xor(s0, off);
            s1 += __shfl_xor(s1, off);
        }
        float inv0 = 1.f / (s0 + 1e-16f), inv1 = 1.f / (s1 + 1e-16f);
        for (int base = p0; base < p1; base += 64) {
            int e = base + lane;
            float eal0 = 0.f, eal1 = 0.f, ewq = 0.f; int es = 0;
            if (e < p1) {
                es = src_sorted[e];
                ewq = w_sorted[e];
                float2 a2 = ((const float2*)a_src)[es];
                float v0 = a2.x + ad2.x; v0 = (v0 > 0.f) ? v0 : 0.2f * v0;
                float v1 = a2.y + ad2.y; v1 = (v1 > 0.f) ? v1 : 0.2f * v1;
                eal0 = __expf(v0 - m0) * inv0;
                eal1 = __expf(v1 - m1) * inv1;
            }
            int nc = min(64, p1 - base);
            for (int j = 0; j < nc; ++j) {
                float a0 = __shfl(eal0, j);
                float a1 = __shfl(eal1, j);
                float wq = __shfl(ewq, j);
                int   s  = __shfl(es, j);
                float al = (lane < 32) ? a0 : a1;
                float2 f = __half22float2(xp_h[(size_t)s * 64 + lane]);
                float xq = __half2float(xq_h[(size_t)s * 64 + lane]);
                gacc.x = fmaf(al, f.x, gacc.x);
                gacc.y = fmaf(al, f.y, gacc.y);
                sacc   = fmaf(wq, xq, sacc);
            }
        }
    }

    // epilogue: GAT cols 0..127 (float2/lane), SG col 128+lane
    float2 gb2 = ((const float2*)gat_b)[lane];
    float2 og = { fmaxf(gacc.x + gb2.x, 0.f), fmaxf(gacc.y + gb2.y, 0.f) };
    *(float2*)&xout[(size_t)d * 192 + 2 * lane] = og;
    float did = dinv[d];
    float os = fmaf(did, sacc, sg_b[lane]);
    xout[(size_t)d * 192 + 128 + lane] = fmaxf(os, 0.f);
}

// ------------------------------------------------------------------------------
extern "C" void kernel_launch(void* const* d_in, const int* in_sizes, int n_in,
                              void* d_out, int out_size, void* d_ws, size_t ws_size,
                              hipStream_t stream) {
    const float* x   = (const float*)d_in[0];
    const int*   ei  = (const int*)d_in[1];
    const float* ew  = (const float*)d_in[2];
    const int* src = ei;
    const int* dst = ei + NE;

    const float* P[2][8];
    for (int l = 0; l < 2; ++l)
        for (int j = 0; j < 8; ++j)
            P[l][j] = (const float*)d_in[3 + l * 8 + j];
    const float* cls_W = (const float*)d_in[19];
    const float* cls_b = (const float*)d_in[20];

    float* ws = (float*)d_ws;
    const size_t n = NN;
    float* xh    = ws;                        // 64N fp32
    __half2* xp_h = (__half2*)(ws + 64 * n);  // 64N float-slots (128 halves/row)
    __half2* xq_h = (__half2*)(ws + 128 * n); // 32N float-slots (64 halves/row)
    float* a_src = ws + 160 * n;              // 2N
    float* a_dst = ws + 162 * n;              // 2N
    float* dinv  = ws + 164 * n;              // N
    float* xA    = ws + 165 * n;              // 192N
    float* xB    = ws + 357 * n;              // 192N
    int*   row_ptr    = (int*)(ws + 549 * n);        // NN+1
    int*   cnt        = row_ptr + (NN + 1);          // NN (histogram, then cursor)
    int*   bsum       = cnt + NN;                    // 512
    int*   src_sorted = bsum + 512;                  // NES
    float* w_sorted   = (float*)(src_sorted + NES);  // NES

    const int TB = 256;
    int gb_edge = (NES + TB - 1) / TB;
    int gb_node = (NN + TB - 1) / TB;
    int gb_wave4 = (NN + 3) / 4;

    // ---- CSR build + degrees (dinv before fill: w_sorted = w * dinv[src]) ----
    hipMemsetAsync(cnt, 0, NN * sizeof(int), stream);
    hipMemsetAsync(dinv, 0, n * sizeof(float), stream);
    k_histdeg<<<gb_edge, TB, 0, stream>>>(dst, ew, cnt, dinv);
    k_scanA<<<NBLK, TB, 0, stream>>>(cnt, row_ptr, bsum);
    k_scanB<<<1, 512, 0, stream>>>(bsum);
    k_scanC<<<gb_node, TB, 0, stream>>>(row_ptr, bsum);
    k_dinv <<<gb_node, TB, 0, stream>>>(dinv);
    k_fill <<<gb_edge, TB, 0, stream>>>(src, dst, ew, row_ptr, cnt, dinv,
                                        src_sorted, w_sorted);

    const float* xin = x;
    int K = FIN;
    for (int l = 0; l < 2; ++l) {
        const float* pre_W = P[l][0]; const float* pre_b = P[l][1];
        const float* gat_W = P[l][2]; const float* att_s = P[l][3];
        const float* att_d = P[l][4]; const float* gat_b = P[l][5];
        const float* sg_W  = P[l][6]; const float* sg_b  = P[l][7];
        float* xout = (l == 0) ? xA : xB;

        k_pre <<<(NN + 63) / 64, TB, 0, stream>>>(xin, pre_W, pre_b, xh, K);
        k_proj<<<(NN + 31) / 32, TB, 0, stream>>>(xh, gat_W, att_s, att_d,
                                                  xp_h, a_src, a_dst);
        k_sgq <<<(NN + 63) / 64, TB, 0, stream>>>(xh, sg_W, xq_h);
        k_agg <<<gb_wave4, TB, 0, stream>>>(row_ptr, src_sorted, w_sorted, dinv,
                                            a_src, a_dst, xp_h,
                                            (const __half*)xq_h,
                                            gat_b, sg_b, xout);
        xin = xout;
        K = 192;
    }

    k_cls<<<(NN + 127) / 128, TB, 0, stream>>>(xB, cls_W, cls_b, (float*)d_out);
}

// Round 7
// 708.420 us; speedup vs baseline: 1.6193x; 1.2946x over previous
//
#include <hip/hip_runtime.h>
#include <hip/hip_fp16.h>
#include <math.h>

#define NN 100000
#define NE 1200000
#define NES (NE + NN)   // edges incl. self-loops
#define FIN 256
#define NBLK 391        // (NN + 255) / 256

using half8   = __attribute__((ext_vector_type(8))) _Float16;
using floatx4 = __attribute__((ext_vector_type(4))) float;

__device__ __forceinline__ floatx4 mfma16(half8 a, half8 b, floatx4 c) {
    return __builtin_amdgcn_mfma_f32_16x16x32_f16(a, b, c, 0, 0, 0);
}

// ---------------- fused histogram + degree ------------------------------------
__global__ __launch_bounds__(256) void k_histdeg(const int* __restrict__ dst,
                                                 const float* __restrict__ ew,
                                                 int* __restrict__ cnt,
                                                 float* __restrict__ deg) {
    int e = blockIdx.x * 256 + threadIdx.x;
    if (e >= NES) return;
    int d; float w;
    if (e < NE) { d = dst[e]; w = ew[e]; } else { d = e - NE; w = 1.f; }
    atomicAdd(&cnt[d], 1);
    atomicAdd(&deg[d], w);
}
__global__ __launch_bounds__(256) void k_dinv(float* deg) {
    int i = blockIdx.x * 256 + threadIdx.x;
    if (i < NN) { float v = deg[i]; deg[i] = (v > 0.f) ? rsqrtf(v) : 0.f; }
}

// ---------------- CSR build: scan, fill ---------------------------------------
__global__ __launch_bounds__(256) void k_scanA(int* __restrict__ cnt,
                                               int* __restrict__ row_ptr,
                                               int* __restrict__ bsum) {
    __shared__ int tmp[256];
    int tid = threadIdx.x;
    int i = blockIdx.x * 256 + tid;
    int v = (i < NN) ? cnt[i] : 0;
    if (i < NN) cnt[i] = 0;          // re-zero: cnt becomes the fill cursor
    tmp[tid] = v;
    __syncthreads();
    for (int off = 1; off < 256; off <<= 1) {
        int t = (tid >= off) ? tmp[tid - off] : 0;
        __syncthreads();
        tmp[tid] += t;
        __syncthreads();
    }
    if (i < NN) row_ptr[i] = tmp[tid] - v;
    if (tid == 255) bsum[blockIdx.x] = tmp[255];
}

__global__ __launch_bounds__(512) void k_scanB(int* __restrict__ bsum) {
    __shared__ int tmp[512];
    int tid = threadIdx.x;
    int v = (tid < NBLK) ? bsum[tid] : 0;
    tmp[tid] = v;
    __syncthreads();
    for (int off = 1; off < 512; off <<= 1) {
        int t = (tid >= off) ? tmp[tid - off] : 0;
        __syncthreads();
        tmp[tid] += t;
        __syncthreads();
    }
    if (tid < NBLK) bsum[tid] = tmp[tid] - v;
}

__global__ __launch_bounds__(256) void k_scanC(int* __restrict__ row_ptr,
                                               const int* __restrict__ bsum) {
    int i = blockIdx.x * 256 + threadIdx.x;
    if (i < NN) row_ptr[i] += bsum[i >> 8];
    if (i == 0) row_ptr[NN] = NES;
}

// w_sorted stores w * dinv[src]
__global__ __launch_bounds__(256) void k_fill(const int* __restrict__ src,
                                              const int* __restrict__ dst,
                                              const float* __restrict__ ew,
                                              const int* __restrict__ row_ptr,
                                              int* __restrict__ cur,
                                              const float* __restrict__ dinv,
                                              int* __restrict__ src_sorted,
                                              float* __restrict__ w_sorted) {
    int e = blockIdx.x * 256 + threadIdx.x;
    if (e >= NES) return;
    int s, d; float w;
    if (e < NE) { s = src[e]; d = dst[e]; w = ew[e]; } else { s = d = e - NE; w = 1.f; }
    int pos = row_ptr[d] + atomicAdd(&cur[d], 1);
    src_sorted[pos] = s;
    w_sorted[pos] = w * dinv[s];
}

// ---------------- W pre-swizzle into MFMA-fragment-ready fp16 -----------------
// Wf flat index o = (((kc*NT + t)*4 + q)*16 + n)*8 + j  <->  W[kc*32+q*8+j][t*16+n]
__global__ __launch_bounds__(256) void k_wconv(const float* __restrict__ W,
                                               __half* __restrict__ Wf,
                                               int K, int N) {
    int o = blockIdx.x * 256 + threadIdx.x;
    if (o >= K * N) return;
    int j = o & 7, n = (o >> 3) & 15, q = (o >> 7) & 3;
    int rest = o >> 9;
    int NT = N >> 4;
    int t = rest % NT, kc = rest / NT;
    int k = kc * 32 + q * 8 + j;
    Wf[o] = __float2half(W[(size_t)k * N + t * 16 + n]);
}

// fused [gat_W 64x128 | sg_W 64x64] -> Wf with NT=12
__global__ __launch_bounds__(256) void k_wconv2(const float* __restrict__ Wg,
                                                const float* __restrict__ Wsg,
                                                __half* __restrict__ Wf) {
    int o = blockIdx.x * 256 + threadIdx.x;
    if (o >= 64 * 192) return;
    int j = o & 7, n = (o >> 3) & 15, q = (o >> 7) & 3;
    int rest = o >> 9;
    int t = rest % 12, kc = rest / 12;
    int k = kc * 32 + q * 8 + j;
    int c = t * 16 + n;
    float v = (t < 8) ? Wg[(size_t)k * 128 + c] : Wsg[(size_t)k * 64 + (c - 128)];
    Wf[o] = __float2half(v);
}

// ---------------- pre-linear (fp32 A): xh = x @ W[K,64] + b -> fp16 ----------
template<int KK>
__global__ __launch_bounds__(256) void k_pre32(const float* __restrict__ A,
                                               const __half* __restrict__ Wf,
                                               const float* __restrict__ b,
                                               __half* __restrict__ out) {
    int lane = threadIdx.x & 63, wv = threadIdx.x >> 6;
    int q = lane >> 4, n = lane & 15;
    int rowb = blockIdx.x * 64 + wv * 16;
    int rowA = rowb + n; if (rowA > NN - 1) rowA = NN - 1;
    floatx4 acc[4] = {};
    const float* ap = A + (size_t)rowA * KK + q * 8;
    const __half* wp = Wf + q * 128 + n * 8;
    #pragma unroll
    for (int kc = 0; kc < KK / 32; ++kc) {
        float4 f0 = *(const float4*)(ap + kc * 32);
        float4 f1 = *(const float4*)(ap + kc * 32 + 4);
        half8 a;
        a[0] = (_Float16)f0.x; a[1] = (_Float16)f0.y;
        a[2] = (_Float16)f0.z; a[3] = (_Float16)f0.w;
        a[4] = (_Float16)f1.x; a[5] = (_Float16)f1.y;
        a[6] = (_Float16)f1.z; a[7] = (_Float16)f1.w;
        #pragma unroll
        for (int t = 0; t < 4; ++t) {
            half8 bf = *(const half8*)(wp + (size_t)(kc * 4 + t) * 512);
            acc[t] = mfma16(a, bf, acc[t]);
        }
    }
    #pragma unroll
    for (int t = 0; t < 4; ++t) {
        float bb = b[t * 16 + n];
        #pragma unroll
        for (int r = 0; r < 4; ++r) {
            int row = rowb + q * 4 + r;
            if (row < NN)
                out[(size_t)row * 64 + t * 16 + n] = __float2half(acc[t][r] + bb);
        }
    }
}

// ---------------- pre-linear (fp16 A, K=192 stride 192) -----------------------
__global__ __launch_bounds__(256) void k_pre16(const __half* __restrict__ A,
                                               const __half* __restrict__ Wf,
                                               const float* __restrict__ b,
                                               __half* __restrict__ out) {
    int lane = threadIdx.x & 63, wv = threadIdx.x >> 6;
    int q = lane >> 4, n = lane & 15;
    int rowb = blockIdx.x * 64 + wv * 16;
    int rowA = rowb + n; if (rowA > NN - 1) rowA = NN - 1;
    floatx4 acc[4] = {};
    const __half* ap = A + (size_t)rowA * 192 + q * 8;
    const __half* wp = Wf + q * 128 + n * 8;
    #pragma unroll
    for (int kc = 0; kc < 6; ++kc) {
        half8 a = *(const half8*)(ap + kc * 32);
        #pragma unroll
        for (int t = 0; t < 4; ++t) {
            half8 bf = *(const half8*)(wp + (size_t)(kc * 4 + t) * 512);
            acc[t] = mfma16(a, bf, acc[t]);
        }
    }
    #pragma unroll
    for (int t = 0; t < 4; ++t) {
        float bb = b[t * 16 + n];
        #pragma unroll
        for (int r = 0; r < 4; ++r) {
            int row = rowb + q * 4 + r;
            if (row < NN)
                out[(size_t)row * 64 + t * 16 + n] = __float2half(acc[t][r] + bb);
        }
    }
}

// ---------------- fused GAT-proj + SG-proj + attention scores -----------------
// [xp | xq] = xh @ [gat_W | sg_W]  (NT=12 tiles), fp16 outs, fp32 score sums
__global__ __launch_bounds__(256) void k_projq(const __half* __restrict__ A,
                                               const __half* __restrict__ Wf,
                                               const float* __restrict__ att_s,
                                               const float* __restrict__ att_d,
                                               __half* __restrict__ xp,
                                               __half* __restrict__ xq,
                                               float* __restrict__ a_src,
                                               float* __restrict__ a_dst) {
    int lane = threadIdx.x & 63, wv = threadIdx.x >> 6;
    int q = lane >> 4, n = lane & 15;
    int rowb = blockIdx.x * 64 + wv * 16;
    int rowA = rowb + n; if (rowA > NN - 1) rowA = NN - 1;
    floatx4 acc[12] = {};
    const __half* ap = A + (size_t)rowA * 64 + q * 8;
    const __half* wp = Wf + q * 128 + n * 8;
    #pragma unroll
    for (int kc = 0; kc < 2; ++kc) {
        half8 a = *(const half8*)(ap + kc * 32);
        #pragma unroll
        for (int t = 0; t < 12; ++t) {
            half8 bf = *(const half8*)(wp + (size_t)(kc * 12 + t) * 512);
            acc[t] = mfma16(a, bf, acc[t]);
        }
    }
    // attention partial sums: head0 = tiles 0..3, head1 = tiles 4..7
    float vs0[4] = {0,0,0,0}, vs1[4] = {0,0,0,0};
    float vd0[4] = {0,0,0,0}, vd1[4] = {0,0,0,0};
    #pragma unroll
    for (int t = 0; t < 8; ++t) {
        float sv = att_s[t * 16 + n], dv = att_d[t * 16 + n];
        #pragma unroll
        for (int r = 0; r < 4; ++r) {
            float v = acc[t][r];
            if (t < 4) { vs0[r] += v * sv; vd0[r] += v * dv; }
            else       { vs1[r] += v * sv; vd1[r] += v * dv; }
        }
    }
    #pragma unroll
    for (int off = 1; off < 16; off <<= 1) {
        #pragma unroll
        for (int r = 0; r < 4; ++r) {
            vs0[r] += __shfl_xor(vs0[r], off);
            vs1[r] += __shfl_xor(vs1[r], off);
            vd0[r] += __shfl_xor(vd0[r], off);
            vd1[r] += __shfl_xor(vd1[r], off);
        }
    }
    #pragma unroll
    for (int t = 0; t < 8; ++t)
        #pragma unroll
        for (int r = 0; r < 4; ++r) {
            int row = rowb + q * 4 + r;
            if (row < NN) xp[(size_t)row * 128 + t * 16 + n] = __float2half(acc[t][r]);
        }
    #pragma unroll
    for (int t = 8; t < 12; ++t)
        #pragma unroll
        for (int r = 0; r < 4; ++r) {
            int row = rowb + q * 4 + r;
            if (row < NN) xq[(size_t)row * 64 + (t - 8) * 16 + n] = __float2half(acc[t][r]);
        }
    if (n == 0) {
        #pragma unroll
        for (int r = 0; r < 4; ++r) {
            int row = rowb + q * 4 + r;
            if (row < NN) {
                a_src[row * 2]     = vs0[r];
                a_src[row * 2 + 1] = vs1[r];
                a_dst[row * 2]     = vd0[r];
                a_dst[row * 2 + 1] = vd1[r];
            }
        }
    }
}

// ---------------- classifier + log_softmax (MFMA, NT=2) -----------------------
__global__ __launch_bounds__(256) void k_clsm(const __half* __restrict__ A,
                                              const __half* __restrict__ Wf,
                                              const float* __restrict__ b,
                                              float* __restrict__ out) {
    int lane = threadIdx.x & 63, wv = threadIdx.x >> 6;
    int q = lane >> 4, n = lane & 15;
    int rowb = blockIdx.x * 64 + wv * 16;
    int rowA = rowb + n; if (rowA > NN - 1) rowA = NN - 1;
    floatx4 acc[2] = {};
    const __half* ap = A + (size_t)rowA * 192 + q * 8;
    const __half* wp = Wf + q * 128 + n * 8;
    #pragma unroll
    for (int kc = 0; kc < 6; ++kc) {
        half8 a = *(const half8*)(ap + kc * 32);
        #pragma unroll
        for (int t = 0; t < 2; ++t) {
            half8 bf = *(const half8*)(wp + (size_t)(kc * 2 + t) * 512);
            acc[t] = mfma16(a, bf, acc[t]);
        }
    }
    float b0 = b[n], b1 = b[16 + n];
    #pragma unroll
    for (int r = 0; r < 4; ++r) {
        float v0 = acc[0][r] + b0, v1 = acc[1][r] + b1;
        float mx = fmaxf(v0, v1);
        #pragma unroll
        for (int off = 1; off < 16; off <<= 1) mx = fmaxf(mx, __shfl_xor(mx, off));
        float sm = __expf(v0 - mx) + __expf(v1 - mx);
        #pragma unroll
        for (int off = 1; off < 16; off <<= 1) sm += __shfl_xor(sm, off);
        float lg = mx + __logf(sm);
        int row = rowb + q * 4 + r;
        if (row < NN) {
            out[(size_t)row * 32 + n]      = v0 - lg;
            out[(size_t)row * 32 + 16 + n] = v1 - lg;
        }
    }
}

// ---------------- fused GAT + SG aggregation: one wave per dst node -----------
__global__ __launch_bounds__(256) void k_agg(const int* __restrict__ row_ptr,
                                             const int* __restrict__ src_sorted,
                                             const float* __restrict__ w_sorted,
                                             const float* __restrict__ dinv,
                                             const float* __restrict__ a_src,
                                             const float* __restrict__ a_dst,
                                             const __half2* __restrict__ xp_h,
                                             const __half*  __restrict__ xq_h,
                                             const float* __restrict__ gat_b,
                                             const float* __restrict__ sg_b,
                                             __half* __restrict__ xout) {
    int lane = threadIdx.x & 63;
    int d = blockIdx.x * 4 + (threadIdx.x >> 6);
    if (d >= NN) return;
    int p0 = row_ptr[d], p1 = row_ptr[d + 1];
    int nn = p1 - p0;
    float2 ad2 = ((const float2*)a_dst)[d];

    float2 gacc = { 0.f, 0.f };
    float  sacc = 0.f;

    if (nn <= 64) {
        float v0 = -INFINITY, v1 = -INFINITY, ewq = 0.f; int es = 0;
        if (lane < nn) {
            es = src_sorted[p0 + lane];
            ewq = w_sorted[p0 + lane];
            float2 a2 = ((const float2*)a_src)[es];
            v0 = a2.x + ad2.x; v0 = (v0 > 0.f) ? v0 : 0.2f * v0;
            v1 = a2.y + ad2.y; v1 = (v1 > 0.f) ? v1 : 0.2f * v1;
        }
        float m0 = v0, m1 = v1;
        #pragma unroll
        for (int off = 32; off; off >>= 1) {
            m0 = fmaxf(m0, __shfl_xor(m0, off));
            m1 = fmaxf(m1, __shfl_xor(m1, off));
        }
        float e0 = (lane < nn) ? __expf(v0 - m0) : 0.f;
        float e1 = (lane < nn) ? __expf(v1 - m1) : 0.f;
        float s0 = e0, s1 = e1;
        #pragma unroll
        for (int off = 32; off; off >>= 1) {
            s0 += __shfl_xor(s0, off);
            s1 += __shfl_xor(s1, off);
        }
        float eal0 = e0 / (s0 + 1e-16f);
        float eal1 = e1 / (s1 + 1e-16f);
        for (int j = 0; j < nn; ++j) {
            float a0 = __shfl(eal0, j);
            float a1 = __shfl(eal1, j);
            float wq = __shfl(ewq, j);
            int   s  = __shfl(es, j);
            float al = (lane < 32) ? a0 : a1;
            float2 f = __half22float2(xp_h[(size_t)s * 64 + lane]);
            float xq = __half2float(xq_h[(size_t)s * 64 + lane]);
            gacc.x = fmaf(al, f.x, gacc.x);
            gacc.y = fmaf(al, f.y, gacc.y);
            sacc   = fmaf(wq, xq, sacc);
        }
    } else {
        float m0 = -INFINITY, m1 = -INFINITY;
        for (int e = p0 + lane; e < p1; e += 64) {
            int s = src_sorted[e];
            float2 a2 = ((const float2*)a_src)[s];
            float v0 = a2.x + ad2.x; v0 = (v0 > 0.f) ? v0 : 0.2f * v0;
            float v1 = a2.y + ad2.y; v1 = (v1 > 0.f) ? v1 : 0.2f * v1;
            m0 = fmaxf(m0, v0); m1 = fmaxf(m1, v1);
        }
        #pragma unroll
        for (int off = 32; off; off >>= 1) {
            m0 = fmaxf(m0, __shfl_xor(m0, off));
            m1 = fmaxf(m1, __shfl_xor(m1, off));
        }
        float s0 = 0.f, s1 = 0.f;
        for (int e = p0 + lane; e < p1; e += 64) {
            int s = src_sorted[e];
            float2 a2 = ((const float2*)a_src)[s];
            float v0 = a2.x + ad2.x; v0 = (v0 > 0.f) ? v0 : 0.2f * v0;
            float v1 = a2.y + ad2.y; v1 = (v1 > 0.f) ? v1 : 0.2f * v1;
            s0 += __expf(v0 - m0); s1 += __expf(v1 - m1);
        }
        #pragma unroll
        for (int off = 32; off; off >>= 1) {
            s0 += __shfl_xor(s0, off);
            s1 += __shfl_xor(s1, off);
        }
        float inv0 = 1.f / (s0 + 1e-16f), inv1 = 1.f / (s1 + 1e-16f);
        for (int base = p0; base < p1; base += 64) {
            int e = base + lane;
            float eal0 = 0.f, eal1 = 0.f, ewq = 0.f; int es = 0;
            if (e < p1) {
                es = src_sorted[e];
                ewq = w_sorted[e];
                float2 a2 = ((const float2*)a_src)[es];
                float v0 = a2.x + ad2.x; v0 = (v0 > 0.f) ? v0 : 0.2f * v0;
                float v1 = a2.y + ad2.y; v1 = (v1 > 0.f) ? v1 : 0.2f * v1;
                eal0 = __expf(v0 - m0) * inv0;
                eal1 = __expf(v1 - m1) * inv1;
            }
            int nc = min(64, p1 - base);
            for (int j = 0; j < nc; ++j) {
                float a0 = __shfl(eal0, j);
                float a1 = __shfl(eal1, j);
                float wq = __shfl(ewq, j);
                int   s  = __shfl(es, j);
                float al = (lane < 32) ? a0 : a1;
                float2 f = __half22float2(xp_h[(size_t)s * 64 + lane]);
                float xq = __half2float(xq_h[(size_t)s * 64 + lane]);
                gacc.x = fmaf(al, f.x, gacc.x);
                gacc.y = fmaf(al, f.y, gacc.y);
                sacc   = fmaf(wq, xq, sacc);
            }
        }
    }

    float2 gb2 = ((const float2*)gat_b)[lane];
    float2 og = { fmaxf(gacc.x + gb2.x, 0.f), fmaxf(gacc.y + gb2.y, 0.f) };
    *(__half2*)&xout[(size_t)d * 192 + 2 * lane] = __floats2half2_rn(og.x, og.y);
    float did = dinv[d];
    float os = fmaf(did, sacc, sg_b[lane]);
    xout[(size_t)d * 192 + 128 + lane] = __float2half(fmaxf(os, 0.f));
}

// ------------------------------------------------------------------------------
extern "C" void kernel_launch(void* const* d_in, const int* in_sizes, int n_in,
                              void* d_out, int out_size, void* d_ws, size_t ws_size,
                              hipStream_t stream) {
    const float* x   = (const float*)d_in[0];
    const int*   ei  = (const int*)d_in[1];
    const float* ew  = (const float*)d_in[2];
    const int* src = ei;
    const int* dst = ei + NE;

    const float* P[2][8];
    for (int l = 0; l < 2; ++l)
        for (int j = 0; j < 8; ++j)
            P[l][j] = (const float*)d_in[3 + l * 8 + j];
    const float* cls_W = (const float*)d_in[19];
    const float* cls_b = (const float*)d_in[20];

    float* ws = (float*)d_ws;
    const size_t n = NN;
    __half* xh_h = (__half*)(ws);             // [NN][64]  -> 32N float-slots
    __half* xp_h = (__half*)(ws + 32 * n);    // [NN][128] -> 64N
    __half* xq_h = (__half*)(ws + 96 * n);    // [NN][64]  -> 32N
    float* a_src = ws + 128 * n;              // 2N
    float* a_dst = ws + 130 * n;              // 2N
    float* dinv  = ws + 132 * n;              // N
    __half* xA_h = (__half*)(ws + 133 * n);   // [NN][192] -> 96N
    __half* xB_h = (__half*)(ws + 229 * n);   // [NN][192] -> 96N
    float* wfb   = ws + 325 * n;
    __half* Wf_pre0 = (__half*)(wfb);             // 256*64 halves = 8192 fl
    __half* Wf_pre1 = (__half*)(wfb + 8192);      // 192*64 = 6144 fl
    __half* Wf_pq0  = (__half*)(wfb + 14336);     // 64*192 = 6144 fl
    __half* Wf_pq1  = (__half*)(wfb + 20480);     // 64*192 = 6144 fl
    __half* Wf_cls  = (__half*)(wfb + 26624);     // 192*32 = 3072 fl
    int*   row_ptr    = (int*)(wfb + 29696);         // NN+1
    int*   cnt        = row_ptr + (NN + 1);          // NN
    int*   bsum       = cnt + NN;                    // 512
    int*   src_sorted = bsum + 512;                  // NES
    float* w_sorted   = (float*)(src_sorted + NES);  // NES

    const int TB = 256;
    int gb_edge  = (NES + TB - 1) / TB;
    int gb_node  = (NN + TB - 1) / TB;
    int gb_wave4 = (NN + 3) / 4;
    int gb64     = (NN + 63) / 64;   // 1563

    // ---- W pre-swizzle (tiny) ----
    k_wconv <<<64, TB, 0, stream>>>(P[0][0], Wf_pre0, 256, 64);
    k_wconv <<<48, TB, 0, stream>>>(P[1][0], Wf_pre1, 192, 64);
    k_wconv2<<<48, TB, 0, stream>>>(P[0][2], P[0][6], Wf_pq0);
    k_wconv2<<<48, TB, 0, stream>>>(P[1][2], P[1][6], Wf_pq1);
    k_wconv <<<24, TB, 0, stream>>>(cls_W, Wf_cls, 192, 32);

    // ---- CSR build + degrees ----
    hipMemsetAsync(cnt, 0, NN * sizeof(int), stream);
    hipMemsetAsync(dinv, 0, n * sizeof(float), stream);
    k_histdeg<<<gb_edge, TB, 0, stream>>>(dst, ew, cnt, dinv);
    k_scanA<<<NBLK, TB, 0, stream>>>(cnt, row_ptr, bsum);
    k_scanB<<<1, 512, 0, stream>>>(bsum);
    k_scanC<<<gb_node, TB, 0, stream>>>(row_ptr, bsum);
    k_dinv <<<gb_node, TB, 0, stream>>>(dinv);
    k_fill <<<gb_edge, TB, 0, stream>>>(src, dst, ew, row_ptr, cnt, dinv,
                                        src_sorted, w_sorted);

    for (int l = 0; l < 2; ++l) {
        const float* pre_b = P[l][1];
        const float* att_s = P[l][3];
        const float* att_d = P[l][4];
        const float* gat_b = P[l][5];
        const float* sg_b  = P[l][7];
        __half* xout = (l == 0) ? xA_h : xB_h;

        if (l == 0)
            k_pre32<256><<<gb64, TB, 0, stream>>>(x, Wf_pre0, pre_b, xh_h);
        else
            k_pre16<<<gb64, TB, 0, stream>>>(xA_h, Wf_pre1, pre_b, xh_h);
        k_projq<<<gb64, TB, 0, stream>>>(xh_h, (l == 0) ? Wf_pq0 : Wf_pq1,
                                         att_s, att_d, xp_h, xq_h, a_src, a_dst);
        k_agg <<<gb_wave4, TB, 0, stream>>>(row_ptr, src_sorted, w_sorted, dinv,
                                            a_src, a_dst, (const __half2*)xp_h,
                                            (const __half*)xq_h,
                                            gat_b, sg_b, xout);
    }

    k_clsm<<<gb64, TB, 0, stream>>>(xB_h, Wf_cls, cls_b, (float*)d_out);
}

// Round 8
// 644.658 us; speedup vs baseline: 1.7795x; 1.0989x over previous
//
#include <hip/hip_runtime.h>
#include <hip/hip_fp16.h>
#include <math.h>

#define NN 100000
#define NE 1200000
#define NES (NE + NN)   // edges incl. self-loops
#define FIN 256
#define NBLK 391        // (NN + 255) / 256

using half8   = __attribute__((ext_vector_type(8))) _Float16;
using floatx4 = __attribute__((ext_vector_type(4))) float;

__device__ __forceinline__ floatx4 mfma16(half8 a, half8 b, floatx4 c) {
    return __builtin_amdgcn_mfma_f32_16x16x32_f16(a, b, c, 0, 0, 0);
}

// ---------------- fused histogram + degree ------------------------------------
__global__ __launch_bounds__(256) void k_histdeg(const int* __restrict__ dst,
                                                 const float* __restrict__ ew,
                                                 int* __restrict__ cnt,
                                                 float* __restrict__ deg) {
    int e = blockIdx.x * 256 + threadIdx.x;
    if (e >= NES) return;
    int d; float w;
    if (e < NE) { d = dst[e]; w = ew[e]; } else { d = e - NE; w = 1.f; }
    atomicAdd(&cnt[d], 1);
    atomicAdd(&deg[d], w);
}

// ---------------- CSR build: scan (+ dinv fold), fill -------------------------
__global__ __launch_bounds__(256) void k_scanA(int* __restrict__ cnt,
                                               int* __restrict__ row_ptr,
                                               int* __restrict__ bsum,
                                               float* __restrict__ deg) {
    __shared__ int tmp[256];
    int tid = threadIdx.x;
    int i = blockIdx.x * 256 + tid;
    int v = (i < NN) ? cnt[i] : 0;
    if (i < NN) {
        cnt[i] = 0;          // re-zero: cnt becomes the fill cursor
        float dv = deg[i];   // fold k_dinv here (deg complete after histdeg)
        deg[i] = (dv > 0.f) ? rsqrtf(dv) : 0.f;
    }
    tmp[tid] = v;
    __syncthreads();
    for (int off = 1; off < 256; off <<= 1) {
        int t = (tid >= off) ? tmp[tid - off] : 0;
        __syncthreads();
        tmp[tid] += t;
        __syncthreads();
    }
    if (i < NN) row_ptr[i] = tmp[tid] - v;
    if (tid == 255) bsum[blockIdx.x] = tmp[255];
}

__global__ __launch_bounds__(512) void k_scanB(int* __restrict__ bsum) {
    __shared__ int tmp[512];
    int tid = threadIdx.x;
    int v = (tid < NBLK) ? bsum[tid] : 0;
    tmp[tid] = v;
    __syncthreads();
    for (int off = 1; off < 512; off <<= 1) {
        int t = (tid >= off) ? tmp[tid - off] : 0;
        __syncthreads();
        tmp[tid] += t;
        __syncthreads();
    }
    if (tid < NBLK) bsum[tid] = tmp[tid] - v;
}

__global__ __launch_bounds__(256) void k_scanC(int* __restrict__ row_ptr,
                                               const int* __restrict__ bsum) {
    int i = blockIdx.x * 256 + threadIdx.x;
    if (i < NN) row_ptr[i] += bsum[i >> 8];
    if (i == 0) row_ptr[NN] = NES;
}

// w_sorted stores w * dinv[src]
__global__ __launch_bounds__(256) void k_fill(const int* __restrict__ src,
                                              const int* __restrict__ dst,
                                              const float* __restrict__ ew,
                                              const int* __restrict__ row_ptr,
                                              int* __restrict__ cur,
                                              const float* __restrict__ dinv,
                                              int* __restrict__ src_sorted,
                                              float* __restrict__ w_sorted) {
    int e = blockIdx.x * 256 + threadIdx.x;
    if (e >= NES) return;
    int s, d; float w;
    if (e < NE) { s = src[e]; d = dst[e]; w = ew[e]; } else { s = d = e - NE; w = 1.f; }
    int pos = row_ptr[d] + atomicAdd(&cur[d], 1);
    src_sorted[pos] = s;
    w_sorted[pos] = w * dinv[s];
}

// ---------------- single W pre-swizzle kernel (all 5 matrices) ----------------
// Wf layout per segment: o = (((kc*NT + t)*4 + q)*16 + n)*8 + j  <->
//   source k = kc*32+q*8+j, col = t*16+n
__global__ __launch_bounds__(256) void k_wconvall(const float* __restrict__ W0,
                                                  const float* __restrict__ W1,
                                                  const float* __restrict__ Wg0,
                                                  const float* __restrict__ Ws0,
                                                  const float* __restrict__ Wg1,
                                                  const float* __restrict__ Ws1,
                                                  const float* __restrict__ Wc,
                                                  __half* __restrict__ Wf) {
    int o = blockIdx.x * 256 + threadIdx.x;
    if (o >= 59392) return;
    int lo, NT, N; const float* Wg; const float* Wsg = nullptr;
    if (o < 16384)      { lo = o;         NT = 4;  N = 64; Wg = W0; }
    else if (o < 28672) { lo = o - 16384; NT = 4;  N = 64; Wg = W1; }
    else if (o < 40960) { lo = o - 28672; NT = 12; N = 0;  Wg = Wg0; Wsg = Ws0; }
    else if (o < 53248) { lo = o - 40960; NT = 12; N = 0;  Wg = Wg1; Wsg = Ws1; }
    else                { lo = o - 53248; NT = 2;  N = 32; Wg = Wc; }
    int j = lo & 7, n = (lo >> 3) & 15, q = (lo >> 7) & 3, rest = lo >> 9;
    int t = rest % NT, kc = rest / NT;
    int k = kc * 32 + q * 8 + j, col = t * 16 + n;
    float v;
    if (Wsg) v = (col < 128) ? Wg[(size_t)k * 128 + col] : Wsg[(size_t)k * 64 + (col - 128)];
    else     v = Wg[(size_t)k * N + col];
    Wf[o] = __float2half(v);
}

// ---------------- pre-linear (fp32 A): xh = x @ W[K,64] + b -> fp16 ----------
template<int KK>
__global__ __launch_bounds__(256) void k_pre32(const float* __restrict__ A,
                                               const __half* __restrict__ Wf,
                                               const float* __restrict__ b,
                                               __half* __restrict__ out) {
    int lane = threadIdx.x & 63, wv = threadIdx.x >> 6;
    int q = lane >> 4, n = lane & 15;
    int rowb = blockIdx.x * 64 + wv * 16;
    int rowA = rowb + n; if (rowA > NN - 1) rowA = NN - 1;
    floatx4 acc[4] = {};
    const float* ap = A + (size_t)rowA * KK + q * 8;
    const __half* wp = Wf + q * 128 + n * 8;
    #pragma unroll
    for (int kc = 0; kc < KK / 32; ++kc) {
        float4 f0 = *(const float4*)(ap + kc * 32);
        float4 f1 = *(const float4*)(ap + kc * 32 + 4);
        half8 a;
        a[0] = (_Float16)f0.x; a[1] = (_Float16)f0.y;
        a[2] = (_Float16)f0.z; a[3] = (_Float16)f0.w;
        a[4] = (_Float16)f1.x; a[5] = (_Float16)f1.y;
        a[6] = (_Float16)f1.z; a[7] = (_Float16)f1.w;
        #pragma unroll
        for (int t = 0; t < 4; ++t) {
            half8 bf = *(const half8*)(wp + (size_t)(kc * 4 + t) * 512);
            acc[t] = mfma16(a, bf, acc[t]);
        }
    }
    #pragma unroll
    for (int t = 0; t < 4; ++t) {
        float bb = b[t * 16 + n];
        #pragma unroll
        for (int r = 0; r < 4; ++r) {
            int row = rowb + q * 4 + r;
            if (row < NN)
                out[(size_t)row * 64 + t * 16 + n] = __float2half(acc[t][r] + bb);
        }
    }
}

// ---------------- pre-linear (fp16 A, K=192 stride 192) -----------------------
__global__ __launch_bounds__(256) void k_pre16(const __half* __restrict__ A,
                                               const __half* __restrict__ Wf,
                                               const float* __restrict__ b,
                                               __half* __restrict__ out) {
    int lane = threadIdx.x & 63, wv = threadIdx.x >> 6;
    int q = lane >> 4, n = lane & 15;
    int rowb = blockIdx.x * 64 + wv * 16;
    int rowA = rowb + n; if (rowA > NN - 1) rowA = NN - 1;
    floatx4 acc[4] = {};
    const __half* ap = A + (size_t)rowA * 192 + q * 8;
    const __half* wp = Wf + q * 128 + n * 8;
    #pragma unroll
    for (int kc = 0; kc < 6; ++kc) {
        half8 a = *(const half8*)(ap + kc * 32);
        #pragma unroll
        for (int t = 0; t < 4; ++t) {
            half8 bf = *(const half8*)(wp + (size_t)(kc * 4 + t) * 512);
            acc[t] = mfma16(a, bf, acc[t]);
        }
    }
    #pragma unroll
    for (int t = 0; t < 4; ++t) {
        float bb = b[t * 16 + n];
        #pragma unroll
        for (int r = 0; r < 4; ++r) {
            int row = rowb + q * 4 + r;
            if (row < NN)
                out[(size_t)row * 64 + t * 16 + n] = __float2half(acc[t][r] + bb);
        }
    }
}

// ---------------- fused GAT-proj + SG-proj + attention scores -----------------
// xpq[row][0:128]=xp, [128:192]=xq (one merged row: same-page gathers in k_agg)
__global__ __launch_bounds__(256) void k_projq(const __half* __restrict__ A,
                                               const __half* __restrict__ Wf,
                                               const float* __restrict__ att_s,
                                               const float* __restrict__ att_d,
                                               __half* __restrict__ xpq,
                                               float* __restrict__ a_src,
                                               float* __restrict__ a_dst) {
    int lane = threadIdx.x & 63, wv = threadIdx.x >> 6;
    int q = lane >> 4, n = lane & 15;
    int rowb = blockIdx.x * 64 + wv * 16;
    int rowA = rowb + n; if (rowA > NN - 1) rowA = NN - 1;
    floatx4 acc[12] = {};
    const __half* ap = A + (size_t)rowA * 64 + q * 8;
    const __half* wp = Wf + q * 128 + n * 8;
    #pragma unroll
    for (int kc = 0; kc < 2; ++kc) {
        half8 a = *(const half8*)(ap + kc * 32);
        #pragma unroll
        for (int t = 0; t < 12; ++t) {
            half8 bf = *(const half8*)(wp + (size_t)(kc * 12 + t) * 512);
            acc[t] = mfma16(a, bf, acc[t]);
        }
    }
    float vs0[4] = {0,0,0,0}, vs1[4] = {0,0,0,0};
    float vd0[4] = {0,0,0,0}, vd1[4] = {0,0,0,0};
    #pragma unroll
    for (int t = 0; t < 8; ++t) {
        float sv = att_s[t * 16 + n], dv = att_d[t * 16 + n];
        #pragma unroll
        for (int r = 0; r < 4; ++r) {
            float v = acc[t][r];
            if (t < 4) { vs0[r] += v * sv; vd0[r] += v * dv; }
            else       { vs1[r] += v * sv; vd1[r] += v * dv; }
        }
    }
    #pragma unroll
    for (int off = 1; off < 16; off <<= 1) {
        #pragma unroll
        for (int r = 0; r < 4; ++r) {
            vs0[r] += __shfl_xor(vs0[r], off);
            vs1[r] += __shfl_xor(vs1[r], off);
            vd0[r] += __shfl_xor(vd0[r], off);
            vd1[r] += __shfl_xor(vd1[r], off);
        }
    }
    #pragma unroll
    for (int t = 0; t < 12; ++t)
        #pragma unroll
        for (int r = 0; r < 4; ++r) {
            int row = rowb + q * 4 + r;
            if (row < NN) xpq[(size_t)row * 192 + t * 16 + n] = __float2half(acc[t][r]);
        }
    if (n == 0) {
        #pragma unroll
        for (int r = 0; r < 4; ++r) {
            int row = rowb + q * 4 + r;
            if (row < NN) {
                a_src[row * 2]     = vs0[r];
                a_src[row * 2 + 1] = vs1[r];
                a_dst[row * 2]     = vd0[r];
                a_dst[row * 2 + 1] = vd1[r];
            }
        }
    }
}

// ---------------- classifier + log_softmax (MFMA, NT=2) -----------------------
__global__ __launch_bounds__(256) void k_clsm(const __half* __restrict__ A,
                                              const __half* __restrict__ Wf,
                                              const float* __restrict__ b,
                                              float* __restrict__ out) {
    int lane = threadIdx.x & 63, wv = threadIdx.x >> 6;
    int q = lane >> 4, n = lane & 15;
    int rowb = blockIdx.x * 64 + wv * 16;
    int rowA = rowb + n; if (rowA > NN - 1) rowA = NN - 1;
    floatx4 acc[2] = {};
    const __half* ap = A + (size_t)rowA * 192 + q * 8;
    const __half* wp = Wf + q * 128 + n * 8;
    #pragma unroll
    for (int kc = 0; kc < 6; ++kc) {
        half8 a = *(const half8*)(ap + kc * 32);
        #pragma unroll
        for (int t = 0; t < 2; ++t) {
            half8 bf = *(const half8*)(wp + (size_t)(kc * 2 + t) * 512);
            acc[t] = mfma16(a, bf, acc[t]);
        }
    }
    float b0 = b[n], b1 = b[16 + n];
    #pragma unroll
    for (int r = 0; r < 4; ++r) {
        float v0 = acc[0][r] + b0, v1 = acc[1][r] + b1;
        float mx = fmaxf(v0, v1);
        #pragma unroll
        for (int off = 1; off < 16; off <<= 1) mx = fmaxf(mx, __shfl_xor(mx, off));
        float sm = __expf(v0 - mx) + __expf(v1 - mx);
        #pragma unroll
        for (int off = 1; off < 16; off <<= 1) sm += __shfl_xor(sm, off);
        float lg = mx + __logf(sm);
        int row = rowb + q * 4 + r;
        if (row < NN) {
            out[(size_t)row * 32 + n]      = v0 - lg;
            out[(size_t)row * 32 + 16 + n] = v1 - lg;
        }
    }
}

// ---------------- fused GAT + SG aggregation: one wave per dst node -----------
__global__ __launch_bounds__(256) void k_agg(const int* __restrict__ row_ptr,
                                             const int* __restrict__ src_sorted,
                                             const float* __restrict__ w_sorted,
                                             const float* __restrict__ dinv,
                                             const float* __restrict__ a_src,
                                             const float* __restrict__ a_dst,
                                             const __half* __restrict__ xpq,
                                             const float* __restrict__ gat_b,
                                             const float* __restrict__ sg_b,
                                             __half* __restrict__ xout) {
    int lane = threadIdx.x & 63;
    int d = blockIdx.x * 4 + (threadIdx.x >> 6);
    if (d >= NN) return;
    int p0 = row_ptr[d], p1 = row_ptr[d + 1];
    int nn = p1 - p0;
    float2 ad2 = ((const float2*)a_dst)[d];

    float2 gacc = { 0.f, 0.f };
    float  sacc = 0.f;

    if (nn <= 64) {
        // ---- fast path (max degree ~30 for this graph) ----
        float v0 = -INFINITY, v1 = -INFINITY, ewq = 0.f; int es = 0;
        if (lane < nn) {
            es = src_sorted[p0 + lane];
            ewq = w_sorted[p0 + lane];
            float2 a2 = ((const float2*)a_src)[es];
            v0 = a2.x + ad2.x; v0 = (v0 > 0.f) ? v0 : 0.2f * v0;
            v1 = a2.y + ad2.y; v1 = (v1 > 0.f) ? v1 : 0.2f * v1;
        }
        float m0 = v0, m1 = v1;
        #pragma unroll
        for (int off = 32; off; off >>= 1) {
            m0 = fmaxf(m0, __shfl_xor(m0, off));
            m1 = fmaxf(m1, __shfl_xor(m1, off));
        }
        float e0 = (lane < nn) ? __expf(v0 - m0) : 0.f;
        float e1 = (lane < nn) ? __expf(v1 - m1) : 0.f;
        float s0 = e0, s1 = e1;
        #pragma unroll
        for (int off = 32; off; off >>= 1) {
            s0 += __shfl_xor(s0, off);
            s1 += __shfl_xor(s1, off);
        }
        float eal0 = e0 / (s0 + 1e-16f);
        float eal1 = e1 / (s1 + 1e-16f);

        // gather loop, unrolled x4: 8 loads in flight per iteration
        int j = 0;
        for (; j + 4 <= nn; j += 4) {
            int   sA = __shfl(es, j),     sB = __shfl(es, j + 1);
            int   sC = __shfl(es, j + 2), sD = __shfl(es, j + 3);
            float aA0 = __shfl(eal0, j),     aA1 = __shfl(eal1, j);
            float aB0 = __shfl(eal0, j + 1), aB1 = __shfl(eal1, j + 1);
            float aC0 = __shfl(eal0, j + 2), aC1 = __shfl(eal1, j + 2);
            float aD0 = __shfl(eal0, j + 3), aD1 = __shfl(eal1, j + 3);
            float wA = __shfl(ewq, j),     wB = __shfl(ewq, j + 1);
            float wC = __shfl(ewq, j + 2), wD = __shfl(ewq, j + 3);
            const __half* bA = xpq + (size_t)sA * 192;
            const __half* bB = xpq + (size_t)sB * 192;
            const __half* bC = xpq + (size_t)sC * 192;
            const __half* bD = xpq + (size_t)sD * 192;
            __half2 fA = *(const __half2*)(bA + 2 * lane);
            __half2 fB = *(const __half2*)(bB + 2 * lane);
            __half2 fC = *(const __half2*)(bC + 2 * lane);
            __half2 fD = *(const __half2*)(bD + 2 * lane);
            __half  qA = bA[128 + lane], qB = bB[128 + lane];
            __half  qC = bC[128 + lane], qD = bD[128 + lane];
            float alA = (lane < 32) ? aA0 : aA1;
            float alB = (lane < 32) ? aB0 : aB1;
            float alC = (lane < 32) ? aC0 : aC1;
            float alD = (lane < 32) ? aD0 : aD1;
            float2 gA = __half22float2(fA), gB = __half22float2(fB);
            float2 gC = __half22float2(fC), gD = __half22float2(fD);
            gacc.x = fmaf(alA, gA.x, gacc.x); gacc.y = fmaf(alA, gA.y, gacc.y);
            gacc.x = fmaf(alB, gB.x, gacc.x); gacc.y = fmaf(alB, gB.y, gacc.y);
            gacc.x = fmaf(alC, gC.x, gacc.x); gacc.y = fmaf(alC, gC.y, gacc.y);
            gacc.x = fmaf(alD, gD.x, gacc.x); gacc.y = fmaf(alD, gD.y, gacc.y);
            sacc = fmaf(wA, __half2float(qA), sacc);
            sacc = fmaf(wB, __half2float(qB), sacc);
            sacc = fmaf(wC, __half2float(qC), sacc);
            sacc = fmaf(wD, __half2float(qD), sacc);
        }
        for (; j < nn; ++j) {
            int   s  = __shfl(es, j);
            float a0 = __shfl(eal0, j), a1 = __shfl(eal1, j);
            float wq = __shfl(ewq, j);
            const __half* bp = xpq + (size_t)s * 192;
            float2 f = __half22float2(*(const __half2*)(bp + 2 * lane));
            float xq = __half2float(bp[128 + lane]);
            float al = (lane < 32) ? a0 : a1;
            gacc.x = fmaf(al, f.x, gacc.x);
            gacc.y = fmaf(al, f.y, gacc.y);
            sacc   = fmaf(wq, xq, sacc);
        }
    } else {
        // ---- generic 3-pass path (degree > 64; dead for this graph) ----
        float m0 = -INFINITY, m1 = -INFINITY;
        for (int e = p0 + lane; e < p1; e += 64) {
            int s = src_sorted[e];
            float2 a2 = ((const float2*)a_src)[s];
            float v0 = a2.x + ad2.x; v0 = (v0 > 0.f) ? v0 : 0.2f * v0;
            float v1 = a2.y + ad2.y; v1 = (v1 > 0.f) ? v1 : 0.2f * v1;
            m0 = fmaxf(m0, v0); m1 = fmaxf(m1, v1);
        }
        #pragma unroll
        for (int off = 32; off; off >>= 1) {
            m0 = fmaxf(m0, __shfl_xor(m0, off));
            m1 = fmaxf(m1, __shfl_xor(m1, off));
        }
        float s0 = 0.f, s1 = 0.f;
        for (int e = p0 + lane; e < p1; e += 64) {
            int s = src_sorted[e];
            float2 a2 = ((const float2*)a_src)[s];
            float v0 = a2.x + ad2.x; v0 = (v0 > 0.f) ? v0 : 0.2f * v0;
            float v1 = a2.y + ad2.y; v1 = (v1 > 0.f) ? v1 : 0.2f * v1;
            s0 += __expf(v0 - m0); s1 += __expf(v1 - m1);
        }
        #pragma unroll
        for (int off = 32; off; off >>= 1) {
            s0 += __shfl_xor(s0, off);
            s1 += __shfl_xor(s1, off);
        }
        float inv0 = 1.f / (s0 + 1e-16f), inv1 = 1.f / (s1 + 1e-16f);
        for (int base = p0; base < p1; base += 64) {
            int e = base + lane;
            float eal0 = 0.f, eal1 = 0.f, ewq = 0.f; int es = 0;
            if (e < p1) {
                es = src_sorted[e];
                ewq = w_sorted[e];
                float2 a2 = ((const float2*)a_src)[es];
                float v0 = a2.x + ad2.x; v0 = (v0 > 0.f) ? v0 : 0.2f * v0;
                float v1 = a2.y + ad2.y; v1 = (v1 > 0.f) ? v1 : 0.2f * v1;
                eal0 = __expf(v0 - m0) * inv0;
                eal1 = __expf(v1 - m1) * inv1;
            }
            int nc = min(64, p1 - base);
            for (int j = 0; j < nc; ++j) {
                int   s  = __shfl(es, j);
                float a0 = __shfl(eal0, j), a1 = __shfl(eal1, j);
                float wq = __shfl(ewq, j);
                const __half* bp = xpq + (size_t)s * 192;
                float2 f = __half22float2(*(const __half2*)(bp + 2 * lane));
                float xq = __half2float(bp[128 + lane]);
                float al = (lane < 32) ? a0 : a1;
                gacc.x = fmaf(al, f.x, gacc.x);
                gacc.y = fmaf(al, f.y, gacc.y);
                sacc   = fmaf(wq, xq, sacc);
            }
        }
    }

    float2 gb2 = ((const float2*)gat_b)[lane];
    float2 og = { fmaxf(gacc.x + gb2.x, 0.f), fmaxf(gacc.y + gb2.y, 0.f) };
    *(__half2*)&xout[(size_t)d * 192 + 2 * lane] = __floats2half2_rn(og.x, og.y);
    float did = dinv[d];
    float os = fmaf(did, sacc, sg_b[lane]);
    xout[(size_t)d * 192 + 128 + lane] = __float2half(fmaxf(os, 0.f));
}

// ------------------------------------------------------------------------------
extern "C" void kernel_launch(void* const* d_in, const int* in_sizes, int n_in,
                              void* d_out, int out_size, void* d_ws, size_t ws_size,
                              hipStream_t stream) {
    const float* x   = (const float*)d_in[0];
    const int*   ei  = (const int*)d_in[1];
    const float* ew  = (const float*)d_in[2];
    const int* src = ei;
    const int* dst = ei + NE;

    const float* P[2][8];
    for (int l = 0; l < 2; ++l)
        for (int j = 0; j < 8; ++j)
            P[l][j] = (const float*)d_in[3 + l * 8 + j];
    const float* cls_W = (const float*)d_in[19];
    const float* cls_b = (const float*)d_in[20];

    float* ws = (float*)d_ws;
    const size_t n = NN;
    __half* xh_h = (__half*)(ws);             // [NN][64]  halves = 32N fl
    __half* xpq  = (__half*)(ws + 32 * n);    // [NN][192] halves = 96N fl
    float* a_src = ws + 128 * n;              // 2N
    float* a_dst = ws + 130 * n;              // 2N
    __half* xA_h = (__half*)(ws + 132 * n);   // [NN][192] halves = 96N fl
    __half* xB_h = (__half*)(ws + 228 * n);   // [NN][192] halves = 96N fl
    __half* Wf   = (__half*)(ws + 324 * n);   // 59392 halves = 29696 fl
    int*   cnt        = (int*)(ws + 324 * n + 29696);   // NN
    float* dinv       = (float*)(cnt + NN);             // NN (adjacent: 1 memset)
    int*   row_ptr    = (int*)(dinv + NN);              // NN+1
    int*   bsum       = row_ptr + (NN + 1);             // 512
    int*   src_sorted = bsum + 512;                     // NES
    float* w_sorted   = (float*)(src_sorted + NES);     // NES

    __half* Wf_pre0 = Wf;
    __half* Wf_pre1 = Wf + 16384;
    __half* Wf_pq0  = Wf + 28672;
    __half* Wf_pq1  = Wf + 40960;
    __half* Wf_cls  = Wf + 53248;

    const int TB = 256;
    int gb_edge  = (NES + TB - 1) / TB;
    int gb_node  = (NN + TB - 1) / TB;
    int gb_wave4 = (NN + 3) / 4;
    int gb64     = (NN + 63) / 64;

    // ---- all W pre-swizzles in one dispatch ----
    k_wconvall<<<(59392 + TB - 1) / TB, TB, 0, stream>>>(
        P[0][0], P[1][0], P[0][2], P[0][6], P[1][2], P[1][6], cls_W, Wf);

    // ---- CSR build + degrees (cnt & dinv adjacent: single memset) ----
    hipMemsetAsync(cnt, 0, 2 * NN * sizeof(int), stream);
    k_histdeg<<<gb_edge, TB, 0, stream>>>(dst, ew, cnt, dinv);
    k_scanA<<<NBLK, TB, 0, stream>>>(cnt, row_ptr, bsum, dinv);  // + dinv fold
    k_scanB<<<1, 512, 0, stream>>>(bsum);
    k_scanC<<<gb_node, TB, 0, stream>>>(row_ptr, bsum);
    k_fill <<<gb_edge, TB, 0, stream>>>(src, dst, ew, row_ptr, cnt, dinv,
                                        src_sorted, w_sorted);

    for (int l = 0; l < 2; ++l) {
        const float* pre_b = P[l][1];
        const float* att_s = P[l][3];
        const float* att_d = P[l][4];
        const float* gat_b = P[l][5];
        const float* sg_b  = P[l][7];
        __half* xout = (l == 0) ? xA_h : xB_h;

        if (l == 0)
            k_pre32<256><<<gb64, TB, 0, stream>>>(x, Wf_pre0, pre_b, xh_h);
        else
            k_pre16<<<gb64, TB, 0, stream>>>(xA_h, Wf_pre1, pre_b, xh_h);
        k_projq<<<gb64, TB, 0, stream>>>(xh_h, (l == 0) ? Wf_pq0 : Wf_pq1,
                                         att_s, att_d, xpq, a_src, a_dst);
        k_agg <<<gb_wave4, TB, 0, stream>>>(row_ptr, src_sorted, w_sorted, dinv,
                                            a_src, a_dst, xpq,
                                            gat_b, sg_b, xout);
    }

    k_clsm<<<gb64, TB, 0, stream>>>(xB_h, Wf_cls, cls_b, (float*)d_out);
}

// Round 9
// 569.157 us; speedup vs baseline: 2.0156x; 1.1327x over previous
//
#include <hip/hip_runtime.h>
#include <hip/hip_fp16.h>
#include <math.h>

#define NN 100000
#define NE 1200000
#define NES (NE + NN)   // edges incl. self-loops
#define FIN 256
#define NBLK 391        // (NN + 255) / 256

using half8   = __attribute__((ext_vector_type(8))) _Float16;
using floatx4 = __attribute__((ext_vector_type(4))) float;

__device__ __forceinline__ floatx4 mfma16(half8 a, half8 b, floatx4 c) {
    return __builtin_amdgcn_mfma_f32_16x16x32_f16(a, b, c, 0, 0, 0);
}

// ---------------- fused histogram + degree: ONE packed u64 atomic per edge ----
// packed[d]: bits[48:63] = count, bits[0:47] = sum(w) in 2^-32 fixed point.
// w < 1, degree <= ~50  =>  deg sum < 2^38, never carries into the count field.
__global__ __launch_bounds__(256) void k_histdeg(const int* __restrict__ dst,
                                                 const float* __restrict__ ew,
                                                 unsigned long long* __restrict__ packed) {
    int e = blockIdx.x * 256 + threadIdx.x;
    if (e >= NES) return;
    int d; float w;
    if (e < NE) { d = dst[e]; w = ew[e]; } else { d = e - NE; w = 1.f; }
    unsigned long long add = (1ULL << 48)
        + (unsigned long long)((double)w * 4294967296.0);
    atomicAdd(&packed[d], add);
}

// ---------------- CSR build: scan (+ unpack, dinv, cursor-zero), fill ---------
__global__ __launch_bounds__(256) void k_scanA(const unsigned long long* __restrict__ packed,
                                               int* __restrict__ row_ptr,
                                               int* __restrict__ bsum,
                                               float* __restrict__ dinv,
                                               int* __restrict__ cur) {
    __shared__ int tmp[256];
    int tid = threadIdx.x;
    int i = blockIdx.x * 256 + tid;
    int v = 0;
    if (i < NN) {
        unsigned long long p = packed[i];
        v = (int)(p >> 48);
        double deg = (double)(p & 0xFFFFFFFFFFFFULL) * (1.0 / 4294967296.0);
        dinv[i] = (deg > 0.0) ? rsqrtf((float)deg) : 0.f;
        cur[i] = 0;
    }
    tmp[tid] = v;
    __syncthreads();
    for (int off = 1; off < 256; off <<= 1) {
        int t = (tid >= off) ? tmp[tid - off] : 0;
        __syncthreads();
        tmp[tid] += t;
        __syncthreads();
    }
    if (i < NN) row_ptr[i] = tmp[tid] - v;
    if (tid == 255) bsum[blockIdx.x] = tmp[255];
}

__global__ __launch_bounds__(512) void k_scanB(int* __restrict__ bsum) {
    __shared__ int tmp[512];
    int tid = threadIdx.x;
    int v = (tid < NBLK) ? bsum[tid] : 0;
    tmp[tid] = v;
    __syncthreads();
    for (int off = 1; off < 512; off <<= 1) {
        int t = (tid >= off) ? tmp[tid - off] : 0;
        __syncthreads();
        tmp[tid] += t;
        __syncthreads();
    }
    if (tid < NBLK) bsum[tid] = tmp[tid] - v;
}

__global__ __launch_bounds__(256) void k_scanC(int* __restrict__ row_ptr,
                                               const int* __restrict__ bsum) {
    int i = blockIdx.x * 256 + threadIdx.x;
    if (i < NN) row_ptr[i] += bsum[i >> 8];
    if (i == 0) row_ptr[NN] = NES;
}

// edge record: {src, float_bits(w * dinv[src])} — one 8B scattered store
__global__ __launch_bounds__(256) void k_fill(const int* __restrict__ src,
                                              const int* __restrict__ dst,
                                              const float* __restrict__ ew,
                                              const int* __restrict__ row_ptr,
                                              int* __restrict__ cur,
                                              const float* __restrict__ dinv,
                                              int2* __restrict__ recs) {
    int e = blockIdx.x * 256 + threadIdx.x;
    if (e >= NES) return;
    int s, d; float w;
    if (e < NE) { s = src[e]; d = dst[e]; w = ew[e]; } else { s = d = e - NE; w = 1.f; }
    int pos = row_ptr[d] + atomicAdd(&cur[d], 1);
    int2 r; r.x = s; r.y = __float_as_int(w * dinv[s]);
    recs[pos] = r;
}

// ---------------- single W pre-swizzle kernel (all 5 matrices) ----------------
__global__ __launch_bounds__(256) void k_wconvall(const float* __restrict__ W0,
                                                  const float* __restrict__ W1,
                                                  const float* __restrict__ Wg0,
                                                  const float* __restrict__ Ws0,
                                                  const float* __restrict__ Wg1,
                                                  const float* __restrict__ Ws1,
                                                  const float* __restrict__ Wc,
                                                  __half* __restrict__ Wf) {
    int o = blockIdx.x * 256 + threadIdx.x;
    if (o >= 59392) return;
    int lo, NT, N; const float* Wg; const float* Wsg = nullptr;
    if (o < 16384)      { lo = o;         NT = 4;  N = 64; Wg = W0; }
    else if (o < 28672) { lo = o - 16384; NT = 4;  N = 64; Wg = W1; }
    else if (o < 40960) { lo = o - 28672; NT = 12; N = 0;  Wg = Wg0; Wsg = Ws0; }
    else if (o < 53248) { lo = o - 40960; NT = 12; N = 0;  Wg = Wg1; Wsg = Ws1; }
    else                { lo = o - 53248; NT = 2;  N = 32; Wg = Wc; }
    int j = lo & 7, n = (lo >> 3) & 15, q = (lo >> 7) & 3, rest = lo >> 9;
    int t = rest % NT, kc = rest / NT;
    int k = kc * 32 + q * 8 + j, col = t * 16 + n;
    float v;
    if (Wsg) v = (col < 128) ? Wg[(size_t)k * 128 + col] : Wsg[(size_t)k * 64 + (col - 128)];
    else     v = Wg[(size_t)k * N + col];
    Wf[o] = __float2half(v);
}

// ---------------- pre-linear (fp32 A): xh = x @ W[K,64] + b -> fp16 ----------
template<int KK>
__global__ __launch_bounds__(256) void k_pre32(const float* __restrict__ A,
                                               const __half* __restrict__ Wf,
                                               const float* __restrict__ b,
                                               __half* __restrict__ out) {
    int lane = threadIdx.x & 63, wv = threadIdx.x >> 6;
    int q = lane >> 4, n = lane & 15;
    int rowb = blockIdx.x * 64 + wv * 16;
    int rowA = rowb + n; if (rowA > NN - 1) rowA = NN - 1;
    floatx4 acc[4] = {};
    const float* ap = A + (size_t)rowA * KK + q * 8;
    const __half* wp = Wf + q * 128 + n * 8;
    #pragma unroll
    for (int kc = 0; kc < KK / 32; ++kc) {
        float4 f0 = *(const float4*)(ap + kc * 32);
        float4 f1 = *(const float4*)(ap + kc * 32 + 4);
        half8 a;
        a[0] = (_Float16)f0.x; a[1] = (_Float16)f0.y;
        a[2] = (_Float16)f0.z; a[3] = (_Float16)f0.w;
        a[4] = (_Float16)f1.x; a[5] = (_Float16)f1.y;
        a[6] = (_Float16)f1.z; a[7] = (_Float16)f1.w;
        #pragma unroll
        for (int t = 0; t < 4; ++t) {
            half8 bf = *(const half8*)(wp + (size_t)(kc * 4 + t) * 512);
            acc[t] = mfma16(a, bf, acc[t]);
        }
    }
    #pragma unroll
    for (int t = 0; t < 4; ++t) {
        float bb = b[t * 16 + n];
        #pragma unroll
        for (int r = 0; r < 4; ++r) {
            int row = rowb + q * 4 + r;
            if (row < NN)
                out[(size_t)row * 64 + t * 16 + n] = __float2half(acc[t][r] + bb);
        }
    }
}

// ---------------- pre-linear (fp16 A, K=192 stride 192) -----------------------
__global__ __launch_bounds__(256) void k_pre16(const __half* __restrict__ A,
                                               const __half* __restrict__ Wf,
                                               const float* __restrict__ b,
                                               __half* __restrict__ out) {
    int lane = threadIdx.x & 63, wv = threadIdx.x >> 6;
    int q = lane >> 4, n = lane & 15;
    int rowb = blockIdx.x * 64 + wv * 16;
    int rowA = rowb + n; if (rowA > NN - 1) rowA = NN - 1;
    floatx4 acc[4] = {};
    const __half* ap = A + (size_t)rowA * 192 + q * 8;
    const __half* wp = Wf + q * 128 + n * 8;
    #pragma unroll
    for (int kc = 0; kc < 6; ++kc) {
        half8 a = *(const half8*)(ap + kc * 32);
        #pragma unroll
        for (int t = 0; t < 4; ++t) {
            half8 bf = *(const half8*)(wp + (size_t)(kc * 4 + t) * 512);
            acc[t] = mfma16(a, bf, acc[t]);
        }
    }
    #pragma unroll
    for (int t = 0; t < 4; ++t) {
        float bb = b[t * 16 + n];
        #pragma unroll
        for (int r = 0; r < 4; ++r) {
            int row = rowb + q * 4 + r;
            if (row < NN)
                out[(size_t)row * 64 + t * 16 + n] = __float2half(acc[t][r] + bb);
        }
    }
}

// ---------------- fused GAT-proj + SG-proj + attention scores -----------------
__global__ __launch_bounds__(256) void k_projq(const __half* __restrict__ A,
                                               const __half* __restrict__ Wf,
                                               const float* __restrict__ att_s,
                                               const float* __restrict__ att_d,
                                               __half* __restrict__ xpq,
                                               float* __restrict__ a_src,
                                               float* __restrict__ a_dst) {
    int lane = threadIdx.x & 63, wv = threadIdx.x >> 6;
    int q = lane >> 4, n = lane & 15;
    int rowb = blockIdx.x * 64 + wv * 16;
    int rowA = rowb + n; if (rowA > NN - 1) rowA = NN - 1;
    floatx4 acc[12] = {};
    const __half* ap = A + (size_t)rowA * 64 + q * 8;
    const __half* wp = Wf + q * 128 + n * 8;
    #pragma unroll
    for (int kc = 0; kc < 2; ++kc) {
        half8 a = *(const half8*)(ap + kc * 32);
        #pragma unroll
        for (int t = 0; t < 12; ++t) {
            half8 bf = *(const half8*)(wp + (size_t)(kc * 12 + t) * 512);
            acc[t] = mfma16(a, bf, acc[t]);
        }
    }
    float vs0[4] = {0,0,0,0}, vs1[4] = {0,0,0,0};
    float vd0[4] = {0,0,0,0}, vd1[4] = {0,0,0,0};
    #pragma unroll
    for (int t = 0; t < 8; ++t) {
        float sv = att_s[t * 16 + n], dv = att_d[t * 16 + n];
        #pragma unroll
        for (int r = 0; r < 4; ++r) {
            float v = acc[t][r];
            if (t < 4) { vs0[r] += v * sv; vd0[r] += v * dv; }
            else       { vs1[r] += v * sv; vd1[r] += v * dv; }
        }
    }
    #pragma unroll
    for (int off = 1; off < 16; off <<= 1) {
        #pragma unroll
        for (int r = 0; r < 4; ++r) {
            vs0[r] += __shfl_xor(vs0[r], off);
            vs1[r] += __shfl_xor(vs1[r], off);
            vd0[r] += __shfl_xor(vd0[r], off);
            vd1[r] += __shfl_xor(vd1[r], off);
        }
    }
    #pragma unroll
    for (int t = 0; t < 12; ++t)
        #pragma unroll
        for (int r = 0; r < 4; ++r) {
            int row = rowb + q * 4 + r;
            if (row < NN) xpq[(size_t)row * 192 + t * 16 + n] = __float2half(acc[t][r]);
        }
    if (n == 0) {
        #pragma unroll
        for (int r = 0; r < 4; ++r) {
            int row = rowb + q * 4 + r;
            if (row < NN) {
                a_src[row * 2]     = vs0[r];
                a_src[row * 2 + 1] = vs1[r];
                a_dst[row * 2]     = vd0[r];
                a_dst[row * 2 + 1] = vd1[r];
            }
        }
    }
}

// ---------------- classifier + log_softmax (MFMA, NT=2) -----------------------
__global__ __launch_bounds__(256) void k_clsm(const __half* __restrict__ A,
                                              const __half* __restrict__ Wf,
                                              const float* __restrict__ b,
                                              float* __restrict__ out) {
    int lane = threadIdx.x & 63, wv = threadIdx.x >> 6;
    int q = lane >> 4, n = lane & 15;
    int rowb = blockIdx.x * 64 + wv * 16;
    int rowA = rowb + n; if (rowA > NN - 1) rowA = NN - 1;
    floatx4 acc[2] = {};
    const __half* ap = A + (size_t)rowA * 192 + q * 8;
    const __half* wp = Wf + q * 128 + n * 8;
    #pragma unroll
    for (int kc = 0; kc < 6; ++kc) {
        half8 a = *(const half8*)(ap + kc * 32);
        #pragma unroll
        for (int t = 0; t < 2; ++t) {
            half8 bf = *(const half8*)(wp + (size_t)(kc * 2 + t) * 512);
            acc[t] = mfma16(a, bf, acc[t]);
        }
    }
    float b0 = b[n], b1 = b[16 + n];
    #pragma unroll
    for (int r = 0; r < 4; ++r) {
        float v0 = acc[0][r] + b0, v1 = acc[1][r] + b1;
        float mx = fmaxf(v0, v1);
        #pragma unroll
        for (int off = 1; off < 16; off <<= 1) mx = fmaxf(mx, __shfl_xor(mx, off));
        float sm = __expf(v0 - mx) + __expf(v1 - mx);
        #pragma unroll
        for (int off = 1; off < 16; off <<= 1) sm += __shfl_xor(sm, off);
        float lg = mx + __logf(sm);
        int row = rowb + q * 4 + r;
        if (row < NN) {
            out[(size_t)row * 32 + n]      = v0 - lg;
            out[(size_t)row * 32 + 16 + n] = v1 - lg;
        }
    }
}

// ---------------- fused GAT + SG aggregation: one wave per dst node -----------
__global__ __launch_bounds__(256) void k_agg(const int* __restrict__ row_ptr,
                                             const int2* __restrict__ recs,
                                             const float* __restrict__ dinv,
                                             const float* __restrict__ a_src,
                                             const float* __restrict__ a_dst,
                                             const __half* __restrict__ xpq,
                                             const float* __restrict__ gat_b,
                                             const float* __restrict__ sg_b,
                                             __half* __restrict__ xout) {
    int lane = threadIdx.x & 63;
    int d = blockIdx.x * 4 + (threadIdx.x >> 6);
    if (d >= NN) return;
    int p0 = row_ptr[d], p1 = row_ptr[d + 1];
    int nn = p1 - p0;
    float2 ad2 = ((const float2*)a_dst)[d];

    float2 gacc = { 0.f, 0.f };
    float  sacc = 0.f;

    if (nn <= 64) {
        // ---- fast path (max degree ~40 for this graph) ----
        float v0 = -INFINITY, v1 = -INFINITY, ewq = 0.f; int es = 0;
        if (lane < nn) {
            int2 rec = recs[p0 + lane];
            es = rec.x;
            ewq = __int_as_float(rec.y);
            float2 a2 = ((const float2*)a_src)[es];
            v0 = a2.x + ad2.x; v0 = (v0 > 0.f) ? v0 : 0.2f * v0;
            v1 = a2.y + ad2.y; v1 = (v1 > 0.f) ? v1 : 0.2f * v1;
        }
        float m0 = v0, m1 = v1;
        #pragma unroll
        for (int off = 32; off; off >>= 1) {
            m0 = fmaxf(m0, __shfl_xor(m0, off));
            m1 = fmaxf(m1, __shfl_xor(m1, off));
        }
        float e0 = (lane < nn) ? __expf(v0 - m0) : 0.f;
        float e1 = (lane < nn) ? __expf(v1 - m1) : 0.f;
        float s0 = e0, s1 = e1;
        #pragma unroll
        for (int off = 32; off; off >>= 1) {
            s0 += __shfl_xor(s0, off);
            s1 += __shfl_xor(s1, off);
        }
        float eal0 = e0 / (s0 + 1e-16f);
        float eal1 = e1 / (s1 + 1e-16f);

        // gather loop, unrolled x4: 8 loads in flight per iteration
        int j = 0;
        for (; j + 4 <= nn; j += 4) {
            int   sA = __shfl(es, j),     sB = __shfl(es, j + 1);
            int   sC = __shfl(es, j + 2), sD = __shfl(es, j + 3);
            float aA0 = __shfl(eal0, j),     aA1 = __shfl(eal1, j);
            float aB0 = __shfl(eal0, j + 1), aB1 = __shfl(eal1, j + 1);
            float aC0 = __shfl(eal0, j + 2), aC1 = __shfl(eal1, j + 2);
            float aD0 = __shfl(eal0, j + 3), aD1 = __shfl(eal1, j + 3);
            float wA = __shfl(ewq, j),     wB = __shfl(ewq, j + 1);
            float wC = __shfl(ewq, j + 2), wD = __shfl(ewq, j + 3);
            const __half* bA = xpq + (size_t)sA * 192;
            const __half* bB = xpq + (size_t)sB * 192;
            const __half* bC = xpq + (size_t)sC * 192;
            const __half* bD = xpq + (size_t)sD * 192;
            __half2 fA = *(const __half2*)(bA + 2 * lane);
            __half2 fB = *(const __half2*)(bB + 2 * lane);
            __half2 fC = *(const __half2*)(bC + 2 * lane);
            __half2 fD = *(const __half2*)(bD + 2 * lane);
            __half  qA = bA[128 + lane], qB = bB[128 + lane];
            __half  qC = bC[128 + lane], qD = bD[128 + lane];
            float alA = (lane < 32) ? aA0 : aA1;
            float alB = (lane < 32) ? aB0 : aB1;
            float alC = (lane < 32) ? aC0 : aC1;
            float alD = (lane < 32) ? aD0 : aD1;
            float2 gA = __half22float2(fA), gB = __half22float2(fB);
            float2 gC = __half22float2(fC), gD = __half22float2(fD);
            gacc.x = fmaf(alA, gA.x, gacc.x); gacc.y = fmaf(alA, gA.y, gacc.y);
            gacc.x = fmaf(alB, gB.x, gacc.x); gacc.y = fmaf(alB, gB.y, gacc.y);
            gacc.x = fmaf(alC, gC.x, gacc.x); gacc.y = fmaf(alC, gC.y, gacc.y);
            gacc.x = fmaf(alD, gD.x, gacc.x); gacc.y = fmaf(alD, gD.y, gacc.y);
            sacc = fmaf(wA, __half2float(qA), sacc);
            sacc = fmaf(wB, __half2float(qB), sacc);
            sacc = fmaf(wC, __half2float(qC), sacc);
            sacc = fmaf(wD, __half2float(qD), sacc);
        }
        for (; j < nn; ++j) {
            int   s  = __shfl(es, j);
            float a0 = __shfl(eal0, j), a1 = __shfl(eal1, j);
            float wq = __shfl(ewq, j);
            const __half* bp = xpq + (size_t)s * 192;
            float2 f = __half22float2(*(const __half2*)(bp + 2 * lane));
            float xq = __half2float(bp[128 + lane]);
            float al = (lane < 32) ? a0 : a1;
            gacc.x = fmaf(al, f.x, gacc.x);
            gacc.y = fmaf(al, f.y, gacc.y);
            sacc   = fmaf(wq, xq, sacc);
        }
    } else {
        // ---- generic 3-pass path (degree > 64; dead for this graph) ----
        float m0 = -INFINITY, m1 = -INFINITY;
        for (int e = p0 + lane; e < p1; e += 64) {
            int s = recs[e].x;
            float2 a2 = ((const float2*)a_src)[s];
            float v0 = a2.x + ad2.x; v0 = (v0 > 0.f) ? v0 : 0.2f * v0;
            float v1 = a2.y + ad2.y; v1 = (v1 > 0.f) ? v1 : 0.2f * v1;
            m0 = fmaxf(m0, v0); m1 = fmaxf(m1, v1);
        }
        #pragma unroll
        for (int off = 32; off; off >>= 1) {
            m0 = fmaxf(m0, __shfl_xor(m0, off));
            m1 = fmaxf(m1, __shfl_xor(m1, off));
        }
        float s0 = 0.f, s1 = 0.f;
        for (int e = p0 + lane; e < p1; e += 64) {
            int s = recs[e].x;
            float2 a2 = ((const float2*)a_src)[s];
            float v0 = a2.x + ad2.x; v0 = (v0 > 0.f) ? v0 : 0.2f * v0;
            float v1 = a2.y + ad2.y; v1 = (v1 > 0.f) ? v1 : 0.2f * v1;
            s0 += __expf(v0 - m0); s1 += __expf(v1 - m1);
        }
        #pragma unroll
        for (int off = 32; off; off >>= 1) {
            s0 += __shfl_xor(s0, off);
            s1 += __shfl_xor(s1, off);
        }
        float inv0 = 1.f / (s0 + 1e-16f), inv1 = 1.f / (s1 + 1e-16f);
        for (int base = p0; base < p1; base += 64) {
            int e = base + lane;
            float eal0 = 0.f, eal1 = 0.f, ewq = 0.f; int es = 0;
            if (e < p1) {
                int2 rec = recs[e];
                es = rec.x;
                ewq = __int_as_float(rec.y);
                float2 a2 = ((const float2*)a_src)[es];
                float v0 = a2.x + ad2.x; v0 = (v0 > 0.f) ? v0 : 0.2f * v0;
                float v1 = a2.y + ad2.y; v1 = (v1 > 0.f) ? v1 : 0.2f * v1;
                eal0 = __expf(v0 - m0) * inv0;
                eal1 = __expf(v1 - m1) * inv1;
            }
            int nc = min(64, p1 - base);
            for (int j = 0; j < nc; ++j) {
                int   s  = __shfl(es, j);
                float a0 = __shfl(eal0, j), a1 = __shfl(eal1, j);
                float wq = __shfl(ewq, j);
                const __half* bp = xpq + (size_t)s * 192;
                float2 f = __half22float2(*(const __half2*)(bp + 2 * lane));
                float xq = __half2float(bp[128 + lane]);
                float al = (lane < 32) ? a0 : a1;
                gacc.x = fmaf(al, f.x, gacc.x);
                gacc.y = fmaf(al, f.y, gacc.y);
                sacc   = fmaf(wq, xq, sacc);
            }
        }
    }

    float2 gb2 = ((const float2*)gat_b)[lane];
    float2 og = { fmaxf(gacc.x + gb2.x, 0.f), fmaxf(gacc.y + gb2.y, 0.f) };
    *(__half2*)&xout[(size_t)d * 192 + 2 * lane] = __floats2half2_rn(og.x, og.y);
    float did = dinv[d];
    float os = fmaf(did, sacc, sg_b[lane]);
    xout[(size_t)d * 192 + 128 + lane] = __float2half(fmaxf(os, 0.f));
}

// ------------------------------------------------------------------------------
extern "C" void kernel_launch(void* const* d_in, const int* in_sizes, int n_in,
                              void* d_out, int out_size, void* d_ws, size_t ws_size,
                              hipStream_t stream) {
    const float* x   = (const float*)d_in[0];
    const int*   ei  = (const int*)d_in[1];
    const float* ew  = (const float*)d_in[2];
    const int* src = ei;
    const int* dst = ei + NE;

    const float* P[2][8];
    for (int l = 0; l < 2; ++l)
        for (int j = 0; j < 8; ++j)
            P[l][j] = (const float*)d_in[3 + l * 8 + j];
    const float* cls_W = (const float*)d_in[19];
    const float* cls_b = (const float*)d_in[20];

    float* ws = (float*)d_ws;
    const size_t n = NN;
    __half* xh_h = (__half*)(ws);             // [NN][64]  halves = 32N fl
    __half* xpq  = (__half*)(ws + 32 * n);    // [NN][192] halves = 96N fl
    float* a_src = ws + 128 * n;              // 2N
    float* a_dst = ws + 130 * n;              // 2N
    __half* xA_h = (__half*)(ws + 132 * n);   // [NN][192] halves = 96N fl
    __half* xB_h = (__half*)(ws + 228 * n);   // [NN][192] halves = 96N fl
    __half* Wf   = (__half*)(ws + 324 * n);   // 59392 halves = 29696 fl
    float* base2 = ws + 324 * n + 29696;
    unsigned long long* packed = (unsigned long long*)base2;  // NN u64 (align 8: offset even)
    int*   cur        = (int*)(packed + NN);            // NN
    float* dinv       = (float*)(cur + NN);             // NN
    int*   row_ptr    = (int*)(dinv + NN);              // NN+1
    int*   bsum       = row_ptr + (NN + 1);             // 512
    int2*  recs       = (int2*)(bsum + 513);            // NES (8B align ok: odd count pads)

    __half* Wf_pre0 = Wf;
    __half* Wf_pre1 = Wf + 16384;
    __half* Wf_pq0  = Wf + 28672;
    __half* Wf_pq1  = Wf + 40960;
    __half* Wf_cls  = Wf + 53248;

    const int TB = 256;
    int gb_edge  = (NES + TB - 1) / TB;
    int gb_node  = (NN + TB - 1) / TB;
    int gb_wave4 = (NN + 3) / 4;
    int gb64     = (NN + 63) / 64;

    // ---- all W pre-swizzles in one dispatch ----
    k_wconvall<<<(59392 + TB - 1) / TB, TB, 0, stream>>>(
        P[0][0], P[1][0], P[0][2], P[0][6], P[1][2], P[1][6], cls_W, Wf);

    // ---- CSR build + degrees: packed u64 histogram ----
    hipMemsetAsync(packed, 0, NN * sizeof(unsigned long long), stream);
    k_histdeg<<<gb_edge, TB, 0, stream>>>(dst, ew, packed);
    k_scanA<<<NBLK, TB, 0, stream>>>(packed, row_ptr, bsum, dinv, cur);
    k_scanB<<<1, 512, 0, stream>>>(bsum);
    k_scanC<<<gb_node, TB, 0, stream>>>(row_ptr, bsum);
    k_fill <<<gb_edge, TB, 0, stream>>>(src, dst, ew, row_ptr, cur, dinv, recs);

    for (int l = 0; l < 2; ++l) {
        const float* pre_b = P[l][1];
        const float* att_s = P[l][3];
        const float* att_d = P[l][4];
        const float* gat_b = P[l][5];
        const float* sg_b  = P[l][7];
        __half* xout = (l == 0) ? xA_h : xB_h;

        if (l == 0)
            k_pre32<256><<<gb64, TB, 0, stream>>>(x, Wf_pre0, pre_b, xh_h);
        else
            k_pre16<<<gb64, TB, 0, stream>>>(xA_h, Wf_pre1, pre_b, xh_h);
        k_projq<<<gb64, TB, 0, stream>>>(xh_h, (l == 0) ? Wf_pq0 : Wf_pq1,
                                         att_s, att_d, xpq, a_src, a_dst);
        k_agg <<<gb_wave4, TB, 0, stream>>>(row_ptr, recs, dinv,
                                            a_src, a_dst, xpq,
                                            gat_b, sg_b, xout);
    }

    k_clsm<<<gb64, TB, 0, stream>>>(xB_h, Wf_cls, cls_b, (float*)d_out);
}